// Round 6
// baseline (921.399 us; speedup 1.0000x reference)
//
#include <hip/hip_runtime.h>
#include <hip/hip_bf16.h>
#include <hip/hip_fp16.h>

#define Cc 256
#define Nn 32768
#define HWc 16384
#define Bb 2

typedef float floatx4 __attribute__((ext_vector_type(4)));
typedef short bf16x8 __attribute__((ext_vector_type(8)));
typedef unsigned short ushort8v __attribute__((ext_vector_type(8)));
typedef unsigned short ushort4v __attribute__((ext_vector_type(4)));

__device__ __forceinline__ unsigned short f2b(float f){
    unsigned u = __float_as_uint(f);
    u += 0x7fff + ((u >> 16) & 1);
    return (unsigned short)(u >> 16);
}
__device__ __forceinline__ float b2f(unsigned short h){
    return __uint_as_float(((unsigned)h) << 16);
}
__device__ __forceinline__ unsigned short f2h(float f){
    return __half_as_ushort(__float2half(f));
}
__device__ __forceinline__ float h2f(unsigned short h){
    return __half2float(__ushort_as_half(h));
}

// ---------------- setup kernels ----------------
__global__ __launch_bounds__(256) void k_count(const int* __restrict__ ci,
                                               const float* __restrict__ occ,
                                               float* __restrict__ fcounts,
                                               int* __restrict__ icounts){
    int idx = blockIdx.x*256 + threadIdx.x;
    if (idx >= Bb*3*Nn) return;
    int n = idx & (Nn-1);
    int bg = idx >> 15;           // b*3+g
    int b = bg / 3;
    int cell = min(max(ci[idx], 0), HWc-1);
    float o = occ[(b<<15) + n];
    atomicAdd(&fcounts[(bg<<14) + cell], o*o);
    atomicAdd(&icounts[(bg<<14) + cell], 1);
}

__global__ __launch_bounds__(256) void k_wpt(const int* __restrict__ ci,
                                             const float* __restrict__ occ,
                                             const float* __restrict__ fcounts,
                                             float* __restrict__ wpt){
    int idx = blockIdx.x*256 + threadIdx.x;
    if (idx >= Bb*3*Nn) return;
    int n = idx & (Nn-1);
    int bg = idx >> 15;
    int b = bg / 3;
    int cell = min(max(ci[idx], 0), HWc-1);
    float o = occ[(b<<15) + n];
    float cnt = fcounts[(bg<<14) + cell];
    wpt[idx] = o / (o*cnt + 1e-6f);
}

// exclusive prefix scan of per-cell int counts -> starts[HW+1], cursors copy
__global__ __launch_bounds__(256) void k_scan(const int* __restrict__ ic,
                                              int* __restrict__ starts,
                                              int* __restrict__ cursor){
    __shared__ int part[256];
    int bg = blockIdx.x;          // 0..5
    int t = threadIdx.x;
    const int* cs = ic + (bg << 14);
    int base = t * 64;
    int s = 0;
    for (int i = 0; i < 64; ++i) s += cs[base + i];
    part[t] = s;
    __syncthreads();
    for (int off = 1; off < 256; off <<= 1){
        int v = (t >= off) ? part[t - off] : 0;
        __syncthreads();
        part[t] += v;
        __syncthreads();
    }
    int run = (t == 0) ? 0 : part[t - 1];
    int* st = starts + bg * (HWc + 1);
    int* cu = cursor + (bg << 14);
    for (int i = 0; i < 64; ++i){
        st[base + i] = run;
        cu[base + i] = run;
        run += cs[base + i];
    }
    if (t == 255) st[HWc] = run;
}

__global__ __launch_bounds__(256) void k_fill(const int* __restrict__ ci,
                                              int* __restrict__ cursor,
                                              int* __restrict__ plist){
    int idx = blockIdx.x*256 + threadIdx.x;
    if (idx >= Bb*3*Nn) return;
    int n = idx & (Nn-1);
    int bg = idx >> 15;
    int cell = min(max(ci[idx], 0), HWc-1);
    int pos = atomicAdd(&cursor[(bg<<14) + cell], 1);
    plist[(bg<<15) + pos] = n;
}

__global__ __launch_bounds__(256) void k_wcvt(const float* __restrict__ w1,
                                              const float* __restrict__ w2,
                                              unsigned short* __restrict__ W1b,
                                              unsigned short* __restrict__ W2b){
    int idx = blockIdx.x*256 + threadIdx.x;
    if (idx >= 4*Cc*Cc) return;
    W1b[idx] = f2b(w1[idx]);
    W2b[idx] = f2b(w2[idx]);
}

// ---------------- K1a (depth 0 only): LayerNorm(smix) * wpt -> rbuf [b][n][c] fp16 ----------------
__global__ __launch_bounds__(256) void k1a_ln(const float* __restrict__ tok,
                                              const float* __restrict__ wpt,
                                              const float* __restrict__ lng,
                                              const float* __restrict__ lnb,
                                              unsigned short* __restrict__ rbuf, int g){
    __shared__ float lg[Cc], lb[Cc];
    int t = threadIdx.x;
    lg[t] = lng[t];
    lb[t] = lnb[t];
    __syncthreads();
    int b = blockIdx.x >> 7;               // 128 blocks per batch, 256 points each
    int p = ((blockIdx.x & 127) << 8) + t;
    const float* tb = tok + ((size_t)b << 8)*Nn + p;
    float sum = 0.f, sq = 0.f;
    for (int c = 0; c < Cc; ++c){
        float x = tb[(size_t)c << 15];
        sum += x; sq += x*x;
    }
    float m = sum * (1.f/256.f);
    float v = sq * (1.f/256.f) - m*m;
    float r = rsqrtf(fmaxf(v, 0.f) + 1e-5f);
    float wv = wpt[(b*3 + g)*Nn + p];
    unsigned short* rb = rbuf + ((size_t)((b << 15) + p) << 8);
    for (int c0 = 0; c0 < Cc; c0 += 8){
        ushort8v u;
        #pragma unroll
        for (int j = 0; j < 8; ++j){
            int c = c0 + j;
            float x = tb[(size_t)c << 15];
            float h = ((x - m)*r*lg[c] + lb[c]) * wv;
            u[j] = f2h(h);
        }
        *(ushort8v*)(rb + c0) = u;
    }
}

// ---------------- K1b: CSR gather rbuf -> grid fp16 [b][c][hw], no atomics ----------------
// 8 cells/block (was 16): halves the serial dependent-load chain per block, 2x block
// parallelism for this latency-bound gather. Single ushort8 store per thread.
__global__ __launch_bounds__(256) void k1b_gather(const unsigned short* __restrict__ rbuf,
                                                  const int* __restrict__ starts,
                                                  const int* __restrict__ plist,
                                                  unsigned short* __restrict__ grid, int g){
    int t = threadIdx.x;                   // channel
    int bi = blockIdx.x;                   // Bb * (HW/8)
    int b = bi >> 11;
    int cell0 = (bi & 2047) << 3;
    int bg = b*3 + g;
    const int* st = starts + bg*(HWc + 1) + cell0;
    const int* pl = plist + (bg << 15);
    const unsigned short* rb = rbuf + (((size_t)b << 15) << 8);
    float acc[8];
    int s0 = st[0];
    #pragma unroll
    for (int q = 0; q < 8; ++q){
        int s1 = st[q + 1];
        float a = 0.f;
        for (int j = s0; j < s1; ++j){
            int p = pl[j];
            a += h2f(rb[((size_t)p << 8) + t]);
        }
        acc[q] = a;
        s0 = s1;
    }
    unsigned short* go = grid + ((size_t)((b << 8) + t))*HWc + cell0;
    ushort8v u;
    #pragma unroll
    for (int e = 0; e < 8; ++e) u[e] = f2h(acc[e]);
    *(ushort8v*)go = u;
}

// ---------------- K2: fused dwconv3 -> relu -> dwconv3 (+skip) + BN partial sums (fp16 IO) ------
__global__ __launch_bounds__(256) void k2_conv(const unsigned short* __restrict__ grid,
                                               const unsigned short* __restrict__ skip,
                                               unsigned short* __restrict__ plane,
                                               const float* __restrict__ w1, const float* __restrict__ b1,
                                               const float* __restrict__ w2, const float* __restrict__ b2,
                                               const float* __restrict__ asc,
                                               float* __restrict__ bnS, float* __restrict__ bnQ,
                                               int useskip){
    __shared__ float it[36*132];
    __shared__ float mid[34*132];
    int tid = threadIdx.x;
    int bi = blockIdx.x;
    int rt = bi & 3;
    int bc = bi >> 2;              // b*256+c
    int c = bc & 255;
    int r0 = rt << 5;
    const unsigned short* src = grid + (size_t)bc*HWc;
    const unsigned short* sk  = skip + (size_t)bc*HWc;
    // zero the 4 halo columns of every row
    for (int i = tid; i < 36; i += 256){
        it[i*132 + 0] = 0.f; it[i*132 + 1] = 0.f;
        it[i*132 + 130] = 0.f; it[i*132 + 131] = 0.f;
    }
    // interior: 36 rows x 16 chunks of 8 px (vector loads)
    for (int i = tid; i < 36*16; i += 256){
        int r = i >> 4, ch = i & 15;
        int gy = r0 - 2 + r;
        float vals[8];
        #pragma unroll
        for (int e = 0; e < 8; ++e) vals[e] = 0.f;
        if ((unsigned)gy < 128u){
            ushort8v sv = *(const ushort8v*)(src + (gy << 7) + ch*8);
            if (useskip){
                ushort8v kv = *(const ushort8v*)(sk + (gy << 7) + ch*8);
                #pragma unroll
                for (int e = 0; e < 8; ++e) vals[e] = h2f(sv[e]) + h2f(kv[e]);
            } else {
                #pragma unroll
                for (int e = 0; e < 8; ++e) vals[e] = h2f(sv[e]);
            }
        }
        #pragma unroll
        for (int e = 0; e < 8; ++e) it[r*132 + 2 + ch*8 + e] = vals[e];
    }
    float a1[9], a2[9];
    #pragma unroll
    for (int j = 0; j < 9; ++j){ a1[j] = w1[c*9+j]; a2[j] = w2[c*9+j]; }
    float bb1 = b1[c], bb2 = b2[c], sc = asc[c];
    __syncthreads();
    for (int i = tid; i < 34*130; i += 256){
        int r = i / 130, cc = i - r*130;
        int y = r0 - 1 + r, x = cc - 1;
        float v = 0.f;
        if ((unsigned)y < 128u && (unsigned)x < 128u){
            float s = 0.f;
            #pragma unroll
            for (int j = 0; j < 9; ++j) s += a1[j] * it[(r + j/3)*132 + cc + (j%3)];
            v = fmaxf(s + bb1, 0.f);
        }
        mid[r*132 + cc] = v;
    }
    __syncthreads();
    float ps = 0.f, pq = 0.f;
    unsigned short* dst = plane + (size_t)bc*HWc;
    // output: 32 rows x 32 chunks of 4 px (vector stores)
    for (int i = tid; i < 32*32; i += 256){
        int yy = i >> 5, ch = i & 31;
        int x0 = ch << 2;
        ushort4v u;
        #pragma unroll
        for (int e = 0; e < 4; ++e){
            int x = x0 + e;
            float s = 0.f;
            #pragma unroll
            for (int j = 0; j < 9; ++j) s += a2[j] * mid[(yy + j/3)*132 + x + (j%3)];
            float v = s + bb2;
            u[e] = f2h(v);
            float t = v * sc;
            ps += t; pq += t*t;
        }
        *(ushort4v*)(dst + ((r0 + yy) << 7) + x0) = u;
    }
    __syncthreads();
    it[tid] = ps; it[256 + tid] = pq;
    __syncthreads();
    for (int s2 = 128; s2 > 0; s2 >>= 1){
        if (tid < s2){ it[tid] += it[tid+s2]; it[256+tid] += it[256+tid+s2]; }
        __syncthreads();
    }
    if (tid == 0){
        atomicAdd(&bnS[c], it[0]);
        atomicAdd(&bnQ[c], it[256]);
    }
}

// ---------------- K3t: BN fold + sigmoid gate + transpose plane -> attp fp16 [b][hw][c] ----------
__global__ __launch_bounds__(256) void k3t_att_t(const unsigned short* __restrict__ plane,
                                                 const float* __restrict__ bnS, const float* __restrict__ bnQ,
                                                 const float* __restrict__ asc,
                                                 const float* __restrict__ bng, const float* __restrict__ bnb,
                                                 unsigned short* __restrict__ attp){
    __shared__ float t[32*33];
    __shared__ float P_s[32], Q_s[32];
    int tid = threadIdx.x;
    int tx = tid & 31, ty = tid >> 5;
    int bi = blockIdx.x;
    int ht = bi & 511;
    int ct = (bi >> 9) & 7;
    int b  = bi >> 12;
    int c0 = ct << 5, h0 = ht << 5;
    if (tid < 32){
        int c = c0 + tid;
        float mean = bnS[c] * (1.f/32768.f);
        float var  = bnQ[c] * (1.f/32768.f) - mean*mean;
        float inv  = rsqrtf(fmaxf(var, 0.f) + 1e-5f) * bng[c];
        P_s[tid] = asc[c] * inv;
        Q_s[tid] = bnb[c] - mean * inv;
    }
    __syncthreads();
    for (int r = ty; r < 32; r += 8){
        int c = c0 + r;
        float v = h2f(plane[(((size_t)b << 8) + c)*HWc + h0 + tx]);
        float s = 1.f / (1.f + __expf(-(P_s[r]*v + Q_s[r])));
        t[r*33 + tx] = s * v;
    }
    __syncthreads();
    for (int r = ty; r < 32; r += 8){
        attp[(((size_t)b << 14) + h0 + r)*Cc + c0 + tx] = f2h(t[tx*33 + r]);
    }
}

// ---------------- K4: gather + cmix LN + MFMA mm1(relu) + mm2 + residual + next-depth LN ----------
// 512 threads = 8 waves, 64 points/block. MFMA split into point-half passes so the
// accumulator is 16 AGPRs (not 32): ~76 unified regs -> 6 waves/SIMD -> 3 blocks/CU
// (launch_bounds(512,6) pins the allocator). The two halves touch disjoint hs rows, so
// each half's h1/h2 store overlaps the other half's MFMA. Gather head-start: per-thread
// ci load, attp/token loads issued before param staging and the first barrier.
__global__ __launch_bounds__(512, 6) void k4_cmix(const float* __restrict__ tsrc, int tin_nc,
                                               float* __restrict__ tdst, int tout_nc,
                                               const unsigned short* __restrict__ attp,  // fp16 [b][hw][c]
                                               const int* __restrict__ ci,
                                               const unsigned short* __restrict__ W1,
                                               const unsigned short* __restrict__ W2,
                                               const float* __restrict__ lng, const float* __restrict__ lnb,
                                               const float* __restrict__ b1, const float* __restrict__ b2,
                                               const float* __restrict__ csc,
                                               const float* __restrict__ lng2, const float* __restrict__ lnb2,
                                               const float* __restrict__ wptb,
                                               unsigned short* __restrict__ rbufn,      // fp16 [b][n][c]
                                               int g, int g2, int donext){
    __shared__ __align__(16) unsigned short hs[64*264];    // 33792 B: h -> h1 -> h2
    __shared__ float reds[512], redq[512];
    __shared__ float m_s[64], r_s[64];
    __shared__ float lng_s[Cc], lnb_s[Cc], b1_s[Cc], b2s_s[Cc], cs_s[Cc], g2g_s[Cc], g2b_s[Cc];

    int tid = threadIdx.x;
    int bi = blockIdx.x;
    int b = bi >> 9;               // 512 blocks per batch, 64 points each
    int p0 = (bi & 511) << 6;

    int p  = tid & 63;
    int cg = tid >> 6;
    int c0 = cg << 5;

    // ---- gather head-start: issue random attp loads first ----
    int cell = ci[(b*3 + g)*Nn + p0 + p];
    cell = min(max(cell, 0), HWc-1);
    const unsigned short* ar = attp + ((size_t)((b << 14) + cell))*Cc + c0;
    ushort8v rr[4];
    #pragma unroll
    for (int j = 0; j < 4; ++j) rr[j] = *(const ushort8v*)(ar + 8*j);

    // param staging overlaps the gather latency
    if (tid < 256){
        lng_s[tid] = lng[tid];
        lnb_s[tid] = lnb[tid];
        b1_s[tid]  = b1[tid];
        float cv = csc[tid];
        cs_s[tid]  = cv;
        b2s_s[tid] = b2[tid] * cv;
        g2g_s[tid] = lng2[tid];
        g2b_s[tid] = lnb2[tid];
    }

    float vreg[32];
    float sum = 0.f, sq = 0.f;
    if (tin_nc){
        const floatx4* tn4 = (const floatx4*)(tsrc + ((((size_t)(b << 15)) + p0 + p) << 8) + c0);
        #pragma unroll
        for (int j = 0; j < 8; ++j){
            floatx4 f = tn4[j];
            #pragma unroll
            for (int e = 0; e < 4; ++e){
                int k = j*4 + e;
                float v = f[e] + h2f(rr[k >> 3][k & 7]);
                vreg[k] = v; sum += v; sq += v*v;
            }
        }
    } else {
        const float* tb = tsrc + ((size_t)b << 8)*Nn + p0 + p;
        #pragma unroll
        for (int k = 0; k < 32; ++k){
            float v = tb[(size_t)(c0 + k) << 15] + h2f(rr[k >> 3][k & 7]);
            vreg[k] = v; sum += v; sq += v*v;
        }
    }
    reds[tid] = sum; redq[tid] = sq;
    __syncthreads();              // guards param staging AND reds/redq
    if (tid < 64){
        float s = 0.f, q = 0.f;
        #pragma unroll
        for (int j = 0; j < 8; ++j){ s += reds[j*64 + tid]; q += redq[j*64 + tid]; }
        float m = s * (1.f/256.f);
        float var = q * (1.f/256.f) - m*m;
        m_s[tid] = m;
        r_s[tid] = rsqrtf(fmaxf(var, 0.f) + 1e-5f);
    }
    __syncthreads();
    float mp = m_s[p], rp = r_s[p];
    unsigned short* hrow = &hs[p*264 + c0];
    #pragma unroll
    for (int j = 0; j < 4; ++j){
        ushort8v u;
        #pragma unroll
        for (int e = 0; e < 8; ++e){
            int k = j*8 + e, c = c0 + k;
            u[e] = f2b((vreg[k] - mp)*rp*lng_s[c] + lnb_s[c]);
        }
        *(ushort8v*)(hrow + 8*j) = u;
    }
    __syncthreads();              // B1: h complete

    int lane = tid & 63;
    int w = tid >> 6;              // wave index 0..7 -> output channels w*32..w*32+31
    int l15 = lane & 15;
    int q4 = lane >> 4;
    floatx4 acc[4];               // 16 AGPRs: [mi*2+ni] for the current point-half

    // ---- mm1 pass A: points 0-31 (h rows 0-31) ----
    #pragma unroll
    for (int a = 0; a < 4; ++a) acc[a] = (floatx4){0.f,0.f,0.f,0.f};
    #pragma unroll
    for (int kk = 0; kk < 8; ++kk){
        int k0 = kk*32 + q4*8;
        bf16x8 bfr0 = *(const bf16x8*)&hs[(l15)*264 + k0];
        bf16x8 bfr1 = *(const bf16x8*)&hs[(16 + l15)*264 + k0];
        #pragma unroll
        for (int mi = 0; mi < 2; ++mi){
            bf16x8 af = *(const bf16x8*)&W1[(size_t)(w*32 + mi*16 + l15)*Cc + k0];
            acc[mi*2+0] = __builtin_amdgcn_mfma_f32_16x16x32_bf16(af, bfr0, acc[mi*2+0], 0, 0, 0);
            acc[mi*2+1] = __builtin_amdgcn_mfma_f32_16x16x32_bf16(af, bfr1, acc[mi*2+1], 0, 0, 0);
        }
    }
    __syncthreads();              // B2: all h rows 0-31 reads done
    // store h1-A (rows 0-31) while pass B computes on rows 32-63
    #pragma unroll
    for (int mi = 0; mi < 2; ++mi)
        #pragma unroll
        for (int ni = 0; ni < 2; ++ni){
            int m0 = w*32 + mi*16 + q4*4;
            int nn = ni*16 + l15;
            ushort4v u;
            #pragma unroll
            for (int r = 0; r < 4; ++r)
                u[r] = f2b(fmaxf(acc[mi*2+ni][r] + b1_s[m0 + r], 0.f));
            *(ushort4v*)&hs[nn*264 + m0] = u;
        }
    // ---- mm1 pass B: points 32-63 (h rows 32-63, untouched by h1-A stores) ----
    #pragma unroll
    for (int a = 0; a < 4; ++a) acc[a] = (floatx4){0.f,0.f,0.f,0.f};
    #pragma unroll
    for (int kk = 0; kk < 8; ++kk){
        int k0 = kk*32 + q4*8;
        bf16x8 bfr2 = *(const bf16x8*)&hs[(32 + l15)*264 + k0];
        bf16x8 bfr3 = *(const bf16x8*)&hs[(48 + l15)*264 + k0];
        #pragma unroll
        for (int mi = 0; mi < 2; ++mi){
            bf16x8 af = *(const bf16x8*)&W1[(size_t)(w*32 + mi*16 + l15)*Cc + k0];
            acc[mi*2+0] = __builtin_amdgcn_mfma_f32_16x16x32_bf16(af, bfr2, acc[mi*2+0], 0, 0, 0);
            acc[mi*2+1] = __builtin_amdgcn_mfma_f32_16x16x32_bf16(af, bfr3, acc[mi*2+1], 0, 0, 0);
        }
    }
    __syncthreads();              // B3: h rows 32-63 reads done; h1-A visible
    // store h1-B (rows 32-63) while mm2 pass A reads h1 rows 0-31
    #pragma unroll
    for (int mi = 0; mi < 2; ++mi)
        #pragma unroll
        for (int ni = 0; ni < 2; ++ni){
            int m0 = w*32 + mi*16 + q4*4;
            int nn = 32 + ni*16 + l15;
            ushort4v u;
            #pragma unroll
            for (int r = 0; r < 4; ++r)
                u[r] = f2b(fmaxf(acc[mi*2+ni][r] + b1_s[m0 + r], 0.f));
            *(ushort4v*)&hs[nn*264 + m0] = u;
        }
    // ---- mm2 pass A: points 0-31 (h1 rows 0-31) ----
    #pragma unroll
    for (int a = 0; a < 4; ++a) acc[a] = (floatx4){0.f,0.f,0.f,0.f};
    #pragma unroll
    for (int kk = 0; kk < 8; ++kk){
        int k0 = kk*32 + q4*8;
        bf16x8 bfr0 = *(const bf16x8*)&hs[(l15)*264 + k0];
        bf16x8 bfr1 = *(const bf16x8*)&hs[(16 + l15)*264 + k0];
        #pragma unroll
        for (int mi = 0; mi < 2; ++mi){
            bf16x8 af = *(const bf16x8*)&W2[(size_t)(w*32 + mi*16 + l15)*Cc + k0];
            acc[mi*2+0] = __builtin_amdgcn_mfma_f32_16x16x32_bf16(af, bfr0, acc[mi*2+0], 0, 0, 0);
            acc[mi*2+1] = __builtin_amdgcn_mfma_f32_16x16x32_bf16(af, bfr1, acc[mi*2+1], 0, 0, 0);
        }
    }
    __syncthreads();              // B4: h1 rows 0-31 reads done; h1-B visible
    // store h2-A (rows 0-31) while mm2 pass B reads h1 rows 32-63
    #pragma unroll
    for (int mi = 0; mi < 2; ++mi)
        #pragma unroll
        for (int ni = 0; ni < 2; ++ni){
            int m0 = w*32 + mi*16 + q4*4;
            int nn = ni*16 + l15;
            ushort4v u;
            #pragma unroll
            for (int r = 0; r < 4; ++r)
                u[r] = f2b(acc[mi*2+ni][r]*cs_s[m0 + r] + b2s_s[m0 + r]);
            *(ushort4v*)&hs[nn*264 + m0] = u;
        }
    // ---- mm2 pass B: points 32-63 (h1 rows 32-63) ----
    #pragma unroll
    for (int a = 0; a < 4; ++a) acc[a] = (floatx4){0.f,0.f,0.f,0.f};
    #pragma unroll
    for (int kk = 0; kk < 8; ++kk){
        int k0 = kk*32 + q4*8;
        bf16x8 bfr2 = *(const bf16x8*)&hs[(32 + l15)*264 + k0];
        bf16x8 bfr3 = *(const bf16x8*)&hs[(48 + l15)*264 + k0];
        #pragma unroll
        for (int mi = 0; mi < 2; ++mi){
            bf16x8 af = *(const bf16x8*)&W2[(size_t)(w*32 + mi*16 + l15)*Cc + k0];
            acc[mi*2+0] = __builtin_amdgcn_mfma_f32_16x16x32_bf16(af, bfr2, acc[mi*2+0], 0, 0, 0);
            acc[mi*2+1] = __builtin_amdgcn_mfma_f32_16x16x32_bf16(af, bfr3, acc[mi*2+1], 0, 0, 0);
        }
    }
    __syncthreads();              // B5: h1 rows 32-63 reads done; h2-A visible
    #pragma unroll
    for (int mi = 0; mi < 2; ++mi)
        #pragma unroll
        for (int ni = 0; ni < 2; ++ni){
            int m0 = w*32 + mi*16 + q4*4;
            int nn = 32 + ni*16 + l15;
            ushort4v u;
            #pragma unroll
            for (int r = 0; r < 4; ++r)
                u[r] = f2b(acc[mi*2+ni][r]*cs_s[m0 + r] + b2s_s[m0 + r]);
            *(ushort4v*)&hs[nn*264 + m0] = u;
        }
    __syncthreads();              // B6: h2 complete

    // ---- epilogue: tokens += h2; token write; optional next-depth LN*wpt -> rbuf ----
    float sum2 = 0.f, sq2 = 0.f;
    if (tout_nc){
        float* tn = tdst + ((((size_t)(b << 15)) + p0 + p) << 8) + c0;
        #pragma unroll
        for (int j = 0; j < 4; ++j){
            ushort8v u = *(const ushort8v*)(hrow + 8*j);
            floatx4 fa, fb;
            #pragma unroll
            for (int e = 0; e < 4; ++e){
                int k = j*8 + e;
                float v = vreg[k] + b2f(u[e]);
                vreg[k] = v; fa[e] = v; sum2 += v; sq2 += v*v;
            }
            #pragma unroll
            for (int e = 4; e < 8; ++e){
                int k = j*8 + e;
                float v = vreg[k] + b2f(u[e]);
                vreg[k] = v; fb[e-4] = v; sum2 += v; sq2 += v*v;
            }
            *(floatx4*)(tn + 8*j) = fa;
            *(floatx4*)(tn + 8*j + 4) = fb;
        }
    } else {
        float* ob = tdst + ((size_t)b << 8)*Nn + p0 + p;
        #pragma unroll
        for (int j = 0; j < 4; ++j){
            ushort8v u = *(const ushort8v*)(hrow + 8*j);
            #pragma unroll
            for (int e = 0; e < 8; ++e){
                int k = j*8 + e, c = c0 + k;
                float v = vreg[k] + b2f(u[e]);
                vreg[k] = v;
                ob[(size_t)c << 15] = v;
                sum2 += v; sq2 += v*v;
            }
        }
    }
    if (donext){
        reds[tid] = sum2; redq[tid] = sq2;
        __syncthreads();
        if (tid < 64){
            float s = 0.f, q = 0.f;
            #pragma unroll
            for (int j = 0; j < 8; ++j){ s += reds[j*64 + tid]; q += redq[j*64 + tid]; }
            float m = s * (1.f/256.f);
            float var = q * (1.f/256.f) - m*m;
            m_s[tid] = m;
            r_s[tid] = rsqrtf(fmaxf(var, 0.f) + 1e-5f);
        }
        __syncthreads();
        float m2 = m_s[p], rr2 = r_s[p];
        float wv2 = wptb[(b*3 + g2)*Nn + p0 + p];
        unsigned short* rb = rbufn + ((size_t)((b << 15) + p0 + p))*Cc + c0;
        #pragma unroll
        for (int j = 0; j < 4; ++j){
            ushort8v u;
            #pragma unroll
            for (int e = 0; e < 8; ++e){
                int k = j*8 + e, c = c0 + k;
                u[e] = f2h(((vreg[k] - m2)*rr2*g2g_s[c] + g2b_s[c]) * wv2);
            }
            *(ushort8v*)(rb + 8*j) = u;
        }
    }
}

extern "C" void kernel_launch(void* const* d_in, const int* in_sizes, int n_in,
                              void* d_out, int out_size, void* d_ws, size_t ws_size,
                              hipStream_t stream){
    (void)in_sizes; (void)n_in; (void)out_size;
    const float* tokens  = (const float*)d_in[0];
    const int*   cellind = (const int*)d_in[1];
    const float* occ     = (const float*)d_in[2];
    const float* smix_g  = (const float*)d_in[3];
    const float* smix_b  = (const float*)d_in[4];
    const float* ffn_w1  = (const float*)d_in[5];
    const float* ffn_b1  = (const float*)d_in[6];
    const float* ffn_w2  = (const float*)d_in[7];
    const float* ffn_b2  = (const float*)d_in[8];
    const float* att_sc  = (const float*)d_in[9];
    const float* bn_g    = (const float*)d_in[10];
    const float* bn_b    = (const float*)d_in[11];
    const float* cm_g    = (const float*)d_in[12];
    const float* cm_b    = (const float*)d_in[13];
    const float* cw1     = (const float*)d_in[14];
    const float* cb1     = (const float*)d_in[15];
    const float* cw2     = (const float*)d_in[16];
    const float* cb2     = (const float*)d_in[17];
    const float* cscale  = (const float*)d_in[18];
    float* out = (float*)d_out;
    char* w = (char*)d_ws;

    const size_t HGRID_BYTES = (size_t)Bb*Cc*HWc*2;          // 16777216
    unsigned short* grid_h  = (unsigned short*)(w);
    unsigned short* attp_h  = grid_h;                        // alias: grid dead after k2
    unsigned short* planeA  = (unsigned short*)(w + HGRID_BYTES);
    unsigned short* planeB  = (unsigned short*)(w + 2*HGRID_BYTES);
    unsigned short* rbuf    = (unsigned short*)(w + 3*HGRID_BYTES);  // [b][n][c] fp16, 33.5 MB
    size_t o = 3*HGRID_BYTES + (size_t)Bb*Nn*Cc*2;
    float* fcounts = (float*)(w + o); o += (size_t)Bb*3*HWc*4;
    int*   icounts = (int*)(w + o);   o += (size_t)Bb*3*HWc*4;
    float* wptb   = (float*)(w + o); o += (size_t)Bb*3*Nn*4;
    float* bnS    = (float*)(w + o);
    float* bnQ    = bnS + 256;
    o += 4096;
    unsigned short* W1b = (unsigned short*)(w + o);
    unsigned short* W2b = W1b + 4*Cc*Cc;
    o += (size_t)2*4*Cc*Cc*2;
    int* startsb  = (int*)(w + o); o += (size_t)Bb*3*(HWc+1)*4;
    int* cursors  = (int*)(w + o); o += (size_t)Bb*3*HWc*4;
    int* plistb   = (int*)(w + o); o += (size_t)Bb*3*Nn*4;
    o = (o + 255) & ~(size_t)255;
    float* tnc    = (float*)(w + o);                         // [b][n][c] fp32 intermediate, 64 MB
    size_t needed = o + (size_t)Bb*Nn*Cc*4;
    int nc_ok = (ws_size >= needed) ? 1 : 0;

    // ---- setup (once per launch) ----
    hipMemsetAsync(fcounts, 0, (size_t)2*Bb*3*HWc*4, stream);
    k_count<<<(Bb*3*Nn)/256, 256, 0, stream>>>(cellind, occ, fcounts, icounts);
    k_wpt<<<(Bb*3*Nn)/256, 256, 0, stream>>>(cellind, occ, fcounts, wptb);
    k_scan<<<Bb*3, 256, 0, stream>>>(icounts, startsb, cursors);
    k_fill<<<(Bb*3*Nn)/256, 256, 0, stream>>>(cellind, cursors, plistb);
    k_wcvt<<<(4*Cc*Cc)/256, 256, 0, stream>>>(cw1, cw2, W1b, W2b);

    // depth-0 rbuf from input tokens
    k1a_ln<<<Bb*(Nn/256), 256, 0, stream>>>(tokens, wptb, smix_g, smix_b, rbuf, 0);

    for (int d = 0; d < 4; ++d){
        int g = d % 3;
        int g2 = (d + 1) % 3;
        int donext = (d < 3) ? 1 : 0;
        int useskip = (d == 3) ? 1 : 0;
        unsigned short* plane = (d == 0) ? planeA : planeB;
        int dn = (d + 1 < 4) ? d + 1 : d;   // next depth params (unused when donext=0)

        const float* tsrc; int tin_nc;
        float* tdst; int tout_nc;
        if (nc_ok){
            tsrc = (d == 0) ? tokens : tnc;  tin_nc  = (d == 0) ? 0 : 1;
            tdst = (d == 3) ? out : tnc;     tout_nc = (d == 3) ? 0 : 1;
        } else {
            tsrc = (d == 0) ? tokens : out;  tin_nc  = 0;
            tdst = out;                      tout_nc = 0;
        }

        hipMemsetAsync(bnS, 0, 2048, stream);

        k1b_gather<<<Bb*(HWc/8), 256, 0, stream>>>(rbuf, startsb, plistb, grid_h, g);
        k2_conv<<<Bb*Cc*4, 256, 0, stream>>>(grid_h, planeA, plane,
                                             ffn_w1 + d*Cc*9, ffn_b1 + d*Cc,
                                             ffn_w2 + d*Cc*9, ffn_b2 + d*Cc,
                                             att_sc + d*Cc, bnS, bnQ, useskip);
        k3t_att_t<<<Bb*8*512, 256, 0, stream>>>(plane, bnS, bnQ, att_sc + d*Cc,
                                                bn_g + d*Cc, bn_b + d*Cc, attp_h);
        k4_cmix<<<Bb*(Nn/64), 512, 0, stream>>>(tsrc, tin_nc, tdst, tout_nc, attp_h, cellind,
                                                W1b + (size_t)d*Cc*Cc, W2b + (size_t)d*Cc*Cc,
                                                cm_g + d*Cc, cm_b + d*Cc,
                                                cb1 + d*Cc, cb2 + d*Cc, cscale + d*Cc,
                                                smix_g + dn*Cc, smix_b + dn*Cc, wptb,
                                                rbuf, g, g2, donext);
    }
}

// Round 7
// 757.071 us; speedup vs baseline: 1.2171x; 1.2171x over previous
//
#include <hip/hip_runtime.h>
#include <hip/hip_bf16.h>
#include <hip/hip_fp16.h>

#define Cc 256
#define Nn 32768
#define HWc 16384
#define Bb 2

typedef float floatx4 __attribute__((ext_vector_type(4)));
typedef short bf16x8 __attribute__((ext_vector_type(8)));
typedef unsigned short ushort8v __attribute__((ext_vector_type(8)));
typedef unsigned short ushort4v __attribute__((ext_vector_type(4)));

__device__ __forceinline__ unsigned short f2b(float f){
    unsigned u = __float_as_uint(f);
    u += 0x7fff + ((u >> 16) & 1);
    return (unsigned short)(u >> 16);
}
__device__ __forceinline__ float b2f(unsigned short h){
    return __uint_as_float(((unsigned)h) << 16);
}
__device__ __forceinline__ unsigned short f2h(float f){
    return __half_as_ushort(__float2half(f));
}
__device__ __forceinline__ float h2f(unsigned short h){
    return __half2float(__ushort_as_half(h));
}

// ---------------- setup kernels ----------------
__global__ __launch_bounds__(256) void k_count(const int* __restrict__ ci,
                                               const float* __restrict__ occ,
                                               float* __restrict__ fcounts,
                                               int* __restrict__ icounts){
    int idx = blockIdx.x*256 + threadIdx.x;
    if (idx >= Bb*3*Nn) return;
    int n = idx & (Nn-1);
    int bg = idx >> 15;           // b*3+g
    int b = bg / 3;
    int cell = min(max(ci[idx], 0), HWc-1);
    float o = occ[(b<<15) + n];
    atomicAdd(&fcounts[(bg<<14) + cell], o*o);
    atomicAdd(&icounts[(bg<<14) + cell], 1);
}

__global__ __launch_bounds__(256) void k_wpt(const int* __restrict__ ci,
                                             const float* __restrict__ occ,
                                             const float* __restrict__ fcounts,
                                             float* __restrict__ wpt){
    int idx = blockIdx.x*256 + threadIdx.x;
    if (idx >= Bb*3*Nn) return;
    int n = idx & (Nn-1);
    int bg = idx >> 15;
    int b = bg / 3;
    int cell = min(max(ci[idx], 0), HWc-1);
    float o = occ[(b<<15) + n];
    float cnt = fcounts[(bg<<14) + cell];
    wpt[idx] = o / (o*cnt + 1e-6f);
}

// exclusive prefix scan of per-cell int counts -> starts[HW+1], cursors copy
__global__ __launch_bounds__(256) void k_scan(const int* __restrict__ ic,
                                              int* __restrict__ starts,
                                              int* __restrict__ cursor){
    __shared__ int part[256];
    int bg = blockIdx.x;          // 0..5
    int t = threadIdx.x;
    const int* cs = ic + (bg << 14);
    int base = t * 64;
    int s = 0;
    for (int i = 0; i < 64; ++i) s += cs[base + i];
    part[t] = s;
    __syncthreads();
    for (int off = 1; off < 256; off <<= 1){
        int v = (t >= off) ? part[t - off] : 0;
        __syncthreads();
        part[t] += v;
        __syncthreads();
    }
    int run = (t == 0) ? 0 : part[t - 1];
    int* st = starts + bg * (HWc + 1);
    int* cu = cursor + (bg << 14);
    for (int i = 0; i < 64; ++i){
        st[base + i] = run;
        cu[base + i] = run;
        run += cs[base + i];
    }
    if (t == 255) st[HWc] = run;
}

__global__ __launch_bounds__(256) void k_fill(const int* __restrict__ ci,
                                              int* __restrict__ cursor,
                                              int* __restrict__ plist){
    int idx = blockIdx.x*256 + threadIdx.x;
    if (idx >= Bb*3*Nn) return;
    int n = idx & (Nn-1);
    int bg = idx >> 15;
    int cell = min(max(ci[idx], 0), HWc-1);
    int pos = atomicAdd(&cursor[(bg<<14) + cell], 1);
    plist[(bg<<15) + pos] = n;
}

__global__ __launch_bounds__(256) void k_wcvt(const float* __restrict__ w1,
                                              const float* __restrict__ w2,
                                              unsigned short* __restrict__ W1b,
                                              unsigned short* __restrict__ W2b){
    int idx = blockIdx.x*256 + threadIdx.x;
    if (idx >= 4*Cc*Cc) return;
    W1b[idx] = f2b(w1[idx]);
    W2b[idx] = f2b(w2[idx]);
}

// ---------------- K1a (depth 0 only): LayerNorm(smix) * wpt -> rbuf [b][n][c] fp16 ----------------
__global__ __launch_bounds__(256) void k1a_ln(const float* __restrict__ tok,
                                              const float* __restrict__ wpt,
                                              const float* __restrict__ lng,
                                              const float* __restrict__ lnb,
                                              unsigned short* __restrict__ rbuf, int g){
    __shared__ float lg[Cc], lb[Cc];
    int t = threadIdx.x;
    lg[t] = lng[t];
    lb[t] = lnb[t];
    __syncthreads();
    int b = blockIdx.x >> 7;               // 128 blocks per batch, 256 points each
    int p = ((blockIdx.x & 127) << 8) + t;
    const float* tb = tok + ((size_t)b << 8)*Nn + p;
    float sum = 0.f, sq = 0.f;
    for (int c = 0; c < Cc; ++c){
        float x = tb[(size_t)c << 15];
        sum += x; sq += x*x;
    }
    float m = sum * (1.f/256.f);
    float v = sq * (1.f/256.f) - m*m;
    float r = rsqrtf(fmaxf(v, 0.f) + 1e-5f);
    float wv = wpt[(b*3 + g)*Nn + p];
    unsigned short* rb = rbuf + ((size_t)((b << 15) + p) << 8);
    for (int c0 = 0; c0 < Cc; c0 += 8){
        ushort8v u;
        #pragma unroll
        for (int j = 0; j < 8; ++j){
            int c = c0 + j;
            float x = tb[(size_t)c << 15];
            float h = ((x - m)*r*lg[c] + lb[c]) * wv;
            u[j] = f2h(h);
        }
        *(ushort8v*)(rb + c0) = u;
    }
}

// ---------------- K1b: CSR gather rbuf -> grid fp16 [b][c][hw], no atomics ----------------
// 8 cells/block: halves the serial dependent-load chain per block, 2x block parallelism
// for this latency-bound gather. Single ushort8 store per thread.
__global__ __launch_bounds__(256) void k1b_gather(const unsigned short* __restrict__ rbuf,
                                                  const int* __restrict__ starts,
                                                  const int* __restrict__ plist,
                                                  unsigned short* __restrict__ grid, int g){
    int t = threadIdx.x;                   // channel
    int bi = blockIdx.x;                   // Bb * (HW/8)
    int b = bi >> 11;
    int cell0 = (bi & 2047) << 3;
    int bg = b*3 + g;
    const int* st = starts + bg*(HWc + 1) + cell0;
    const int* pl = plist + (bg << 15);
    const unsigned short* rb = rbuf + (((size_t)b << 15) << 8);
    float acc[8];
    int s0 = st[0];
    #pragma unroll
    for (int q = 0; q < 8; ++q){
        int s1 = st[q + 1];
        float a = 0.f;
        for (int j = s0; j < s1; ++j){
            int p = pl[j];
            a += h2f(rb[((size_t)p << 8) + t]);
        }
        acc[q] = a;
        s0 = s1;
    }
    unsigned short* go = grid + ((size_t)((b << 8) + t))*HWc + cell0;
    ushort8v u;
    #pragma unroll
    for (int e = 0; e < 8; ++e) u[e] = f2h(acc[e]);
    *(ushort8v*)go = u;
}

// ---------------- K2: fused dwconv3 -> relu -> dwconv3 (+skip) + BN partial sums (fp16 IO) ------
__global__ __launch_bounds__(256) void k2_conv(const unsigned short* __restrict__ grid,
                                               const unsigned short* __restrict__ skip,
                                               unsigned short* __restrict__ plane,
                                               const float* __restrict__ w1, const float* __restrict__ b1,
                                               const float* __restrict__ w2, const float* __restrict__ b2,
                                               const float* __restrict__ asc,
                                               float* __restrict__ bnS, float* __restrict__ bnQ,
                                               int useskip){
    __shared__ float it[36*132];
    __shared__ float mid[34*132];
    int tid = threadIdx.x;
    int bi = blockIdx.x;
    int rt = bi & 3;
    int bc = bi >> 2;              // b*256+c
    int c = bc & 255;
    int r0 = rt << 5;
    const unsigned short* src = grid + (size_t)bc*HWc;
    const unsigned short* sk  = skip + (size_t)bc*HWc;
    // zero the 4 halo columns of every row
    for (int i = tid; i < 36; i += 256){
        it[i*132 + 0] = 0.f; it[i*132 + 1] = 0.f;
        it[i*132 + 130] = 0.f; it[i*132 + 131] = 0.f;
    }
    // interior: 36 rows x 16 chunks of 8 px (vector loads)
    for (int i = tid; i < 36*16; i += 256){
        int r = i >> 4, ch = i & 15;
        int gy = r0 - 2 + r;
        float vals[8];
        #pragma unroll
        for (int e = 0; e < 8; ++e) vals[e] = 0.f;
        if ((unsigned)gy < 128u){
            ushort8v sv = *(const ushort8v*)(src + (gy << 7) + ch*8);
            if (useskip){
                ushort8v kv = *(const ushort8v*)(sk + (gy << 7) + ch*8);
                #pragma unroll
                for (int e = 0; e < 8; ++e) vals[e] = h2f(sv[e]) + h2f(kv[e]);
            } else {
                #pragma unroll
                for (int e = 0; e < 8; ++e) vals[e] = h2f(sv[e]);
            }
        }
        #pragma unroll
        for (int e = 0; e < 8; ++e) it[r*132 + 2 + ch*8 + e] = vals[e];
    }
    float a1[9], a2[9];
    #pragma unroll
    for (int j = 0; j < 9; ++j){ a1[j] = w1[c*9+j]; a2[j] = w2[c*9+j]; }
    float bb1 = b1[c], bb2 = b2[c], sc = asc[c];
    __syncthreads();
    for (int i = tid; i < 34*130; i += 256){
        int r = i / 130, cc = i - r*130;
        int y = r0 - 1 + r, x = cc - 1;
        float v = 0.f;
        if ((unsigned)y < 128u && (unsigned)x < 128u){
            float s = 0.f;
            #pragma unroll
            for (int j = 0; j < 9; ++j) s += a1[j] * it[(r + j/3)*132 + cc + (j%3)];
            v = fmaxf(s + bb1, 0.f);
        }
        mid[r*132 + cc] = v;
    }
    __syncthreads();
    float ps = 0.f, pq = 0.f;
    unsigned short* dst = plane + (size_t)bc*HWc;
    // output: 32 rows x 32 chunks of 4 px (vector stores)
    for (int i = tid; i < 32*32; i += 256){
        int yy = i >> 5, ch = i & 31;
        int x0 = ch << 2;
        ushort4v u;
        #pragma unroll
        for (int e = 0; e < 4; ++e){
            int x = x0 + e;
            float s = 0.f;
            #pragma unroll
            for (int j = 0; j < 9; ++j) s += a2[j] * mid[(yy + j/3)*132 + x + (j%3)];
            float v = s + bb2;
            u[e] = f2h(v);
            float t = v * sc;
            ps += t; pq += t*t;
        }
        *(ushort4v*)(dst + ((r0 + yy) << 7) + x0) = u;
    }
    __syncthreads();
    it[tid] = ps; it[256 + tid] = pq;
    __syncthreads();
    for (int s2 = 128; s2 > 0; s2 >>= 1){
        if (tid < s2){ it[tid] += it[tid+s2]; it[256+tid] += it[256+tid+s2]; }
        __syncthreads();
    }
    if (tid == 0){
        atomicAdd(&bnS[c], it[0]);
        atomicAdd(&bnQ[c], it[256]);
    }
}

// ---------------- K3t: BN fold + sigmoid gate + transpose plane -> attp fp16 [b][hw][c] ----------
__global__ __launch_bounds__(256) void k3t_att_t(const unsigned short* __restrict__ plane,
                                                 const float* __restrict__ bnS, const float* __restrict__ bnQ,
                                                 const float* __restrict__ asc,
                                                 const float* __restrict__ bng, const float* __restrict__ bnb,
                                                 unsigned short* __restrict__ attp){
    __shared__ float t[32*33];
    __shared__ float P_s[32], Q_s[32];
    int tid = threadIdx.x;
    int tx = tid & 31, ty = tid >> 5;
    int bi = blockIdx.x;
    int ht = bi & 511;
    int ct = (bi >> 9) & 7;
    int b  = bi >> 12;
    int c0 = ct << 5, h0 = ht << 5;
    if (tid < 32){
        int c = c0 + tid;
        float mean = bnS[c] * (1.f/32768.f);
        float var  = bnQ[c] * (1.f/32768.f) - mean*mean;
        float inv  = rsqrtf(fmaxf(var, 0.f) + 1e-5f) * bng[c];
        P_s[tid] = asc[c] * inv;
        Q_s[tid] = bnb[c] - mean * inv;
    }
    __syncthreads();
    for (int r = ty; r < 32; r += 8){
        int c = c0 + r;
        float v = h2f(plane[(((size_t)b << 8) + c)*HWc + h0 + tx]);
        float s = 1.f / (1.f + __expf(-(P_s[r]*v + Q_s[r])));
        t[r*33 + tx] = s * v;
    }
    __syncthreads();
    for (int r = ty; r < 32; r += 8){
        attp[(((size_t)b << 14) + h0 + r)*Cc + c0 + tx] = f2h(t[tx*33 + r]);
    }
}

// ---------------- K4: gather + cmix LN + MFMA mm1(relu) + mm2 + residual + next-depth LN ----------
// 512 threads = 8 waves, 64 points/block (Round-1/5 structure, best measured: 82 us).
// NOTE (R6 lesson): working set needs ~92-100 unified regs; forcing 6 waves/SIMD via
// launch_bounds spills to scratch (+80MB HBM, 140us). Do not raise the wave bound.
__global__ __launch_bounds__(512, 4) void k4_cmix(const float* __restrict__ tsrc, int tin_nc,
                                               float* __restrict__ tdst, int tout_nc,
                                               const unsigned short* __restrict__ attp,  // fp16 [b][hw][c]
                                               const int* __restrict__ ci,
                                               const unsigned short* __restrict__ W1,
                                               const unsigned short* __restrict__ W2,
                                               const float* __restrict__ lng, const float* __restrict__ lnb,
                                               const float* __restrict__ b1, const float* __restrict__ b2,
                                               const float* __restrict__ csc,
                                               const float* __restrict__ lng2, const float* __restrict__ lnb2,
                                               const float* __restrict__ wptb,
                                               unsigned short* __restrict__ rbufn,      // fp16 [b][n][c]
                                               int g, int g2, int donext){
    __shared__ __align__(16) unsigned short hs[64*264];    // 33792 B: h -> h1 -> h2
    __shared__ float reds[512], redq[512];
    __shared__ float m_s[64], r_s[64];
    __shared__ int cell_s[64];
    __shared__ float lng_s[Cc], lnb_s[Cc], b1_s[Cc], b2s_s[Cc], cs_s[Cc], g2g_s[Cc], g2b_s[Cc];

    int tid = threadIdx.x;
    int bi = blockIdx.x;
    int b = bi >> 9;               // 512 blocks per batch, 64 points each
    int p0 = (bi & 511) << 6;

    if (tid < 256){
        lng_s[tid] = lng[tid];
        lnb_s[tid] = lnb[tid];
        b1_s[tid]  = b1[tid];
        float cv = csc[tid];
        cs_s[tid]  = cv;
        b2s_s[tid] = b2[tid] * cv;
        g2g_s[tid] = lng2[tid];
        g2b_s[tid] = lnb2[tid];
    }
    if (tid < 64){
        int cc = ci[(b*3 + g)*Nn + p0 + tid];
        cell_s[tid] = min(max(cc, 0), HWc-1);
    }
    __syncthreads();

    int p  = tid & 63;
    int cg = tid >> 6;
    int c0 = cg << 5;

    // ---- direct register gather: tokens + attp row chunk (4x16B) ----
    const unsigned short* ar = attp + ((size_t)((b << 14) + cell_s[p]))*Cc + c0;
    ushort8v rr[4];
    #pragma unroll
    for (int j = 0; j < 4; ++j) rr[j] = *(const ushort8v*)(ar + 8*j);

    float vreg[32];
    float sum = 0.f, sq = 0.f;
    if (tin_nc){
        const floatx4* tn4 = (const floatx4*)(tsrc + ((((size_t)(b << 15)) + p0 + p) << 8) + c0);
        #pragma unroll
        for (int j = 0; j < 8; ++j){
            floatx4 f = tn4[j];
            #pragma unroll
            for (int e = 0; e < 4; ++e){
                int k = j*4 + e;
                float v = f[e] + h2f(rr[k >> 3][k & 7]);
                vreg[k] = v; sum += v; sq += v*v;
            }
        }
    } else {
        const float* tb = tsrc + ((size_t)b << 8)*Nn + p0 + p;
        #pragma unroll
        for (int k = 0; k < 32; ++k){
            float v = tb[(size_t)(c0 + k) << 15] + h2f(rr[k >> 3][k & 7]);
            vreg[k] = v; sum += v; sq += v*v;
        }
    }
    reds[tid] = sum; redq[tid] = sq;
    __syncthreads();
    if (tid < 64){
        float s = 0.f, q = 0.f;
        #pragma unroll
        for (int j = 0; j < 8; ++j){ s += reds[j*64 + tid]; q += redq[j*64 + tid]; }
        float m = s * (1.f/256.f);
        float var = q * (1.f/256.f) - m*m;
        m_s[tid] = m;
        r_s[tid] = rsqrtf(fmaxf(var, 0.f) + 1e-5f);
    }
    __syncthreads();
    float mp = m_s[p], rp = r_s[p];
    unsigned short* hrow = &hs[p*264 + c0];
    #pragma unroll
    for (int j = 0; j < 4; ++j){
        ushort8v u;
        #pragma unroll
        for (int e = 0; e < 8; ++e){
            int k = j*8 + e, c = c0 + k;
            u[e] = f2b((vreg[k] - mp)*rp*lng_s[c] + lnb_s[c]);
        }
        *(ushort8v*)(hrow + 8*j) = u;
    }
    __syncthreads();

    int lane = tid & 63;
    int w = tid >> 6;              // wave index 0..7 -> output channels w*32..w*32+31
    int l15 = lane & 15;
    int q4 = lane >> 4;
    floatx4 acc[2][4];
    #pragma unroll
    for (int mi = 0; mi < 2; ++mi)
        #pragma unroll
        for (int ni = 0; ni < 4; ++ni)
            acc[mi][ni] = (floatx4){0.f, 0.f, 0.f, 0.f};

    // mm1: h1 = relu(W1 @ h + b1)
    #pragma unroll
    for (int kk = 0; kk < 8; ++kk){
        int k0 = kk*32 + q4*8;
        bf16x8 bfr[4];
        #pragma unroll
        for (int ni = 0; ni < 4; ++ni)
            bfr[ni] = *(const bf16x8*)&hs[(ni*16 + l15)*264 + k0];
        #pragma unroll
        for (int mi = 0; mi < 2; ++mi){
            bf16x8 af = *(const bf16x8*)&W1[(size_t)(w*32 + mi*16 + l15)*Cc + k0];
            #pragma unroll
            for (int ni = 0; ni < 4; ++ni)
                acc[mi][ni] = __builtin_amdgcn_mfma_f32_16x16x32_bf16(af, bfr[ni], acc[mi][ni], 0, 0, 0);
        }
    }
    __syncthreads();   // all h reads done
    #pragma unroll
    for (int mi = 0; mi < 2; ++mi)
        #pragma unroll
        for (int ni = 0; ni < 4; ++ni){
            int m0 = w*32 + mi*16 + q4*4;
            int nn = ni*16 + l15;
            ushort4v u;
            #pragma unroll
            for (int r = 0; r < 4; ++r)
                u[r] = f2b(fmaxf(acc[mi][ni][r] + b1_s[m0 + r], 0.f));
            *(ushort4v*)&hs[nn*264 + m0] = u;   // h1 [point][channel]
        }
    __syncthreads();

    // mm2: h2 = (W2 @ h1)*cs + b2*cs
    #pragma unroll
    for (int mi = 0; mi < 2; ++mi)
        #pragma unroll
        for (int ni = 0; ni < 4; ++ni)
            acc[mi][ni] = (floatx4){0.f, 0.f, 0.f, 0.f};
    #pragma unroll
    for (int kk = 0; kk < 8; ++kk){
        int k0 = kk*32 + q4*8;
        bf16x8 bfr[4];
        #pragma unroll
        for (int ni = 0; ni < 4; ++ni)
            bfr[ni] = *(const bf16x8*)&hs[(ni*16 + l15)*264 + k0];
        #pragma unroll
        for (int mi = 0; mi < 2; ++mi){
            bf16x8 af = *(const bf16x8*)&W2[(size_t)(w*32 + mi*16 + l15)*Cc + k0];
            #pragma unroll
            for (int ni = 0; ni < 4; ++ni)
                acc[mi][ni] = __builtin_amdgcn_mfma_f32_16x16x32_bf16(af, bfr[ni], acc[mi][ni], 0, 0, 0);
        }
    }
    __syncthreads();   // all h1 reads done
    #pragma unroll
    for (int mi = 0; mi < 2; ++mi)
        #pragma unroll
        for (int ni = 0; ni < 4; ++ni){
            int m0 = w*32 + mi*16 + q4*4;
            int nn = ni*16 + l15;
            ushort4v u;
            #pragma unroll
            for (int r = 0; r < 4; ++r)
                u[r] = f2b(acc[mi][ni][r]*cs_s[m0 + r] + b2s_s[m0 + r]);
            *(ushort4v*)&hs[nn*264 + m0] = u;   // h2 [point][channel]
        }
    __syncthreads();

    // ---- epilogue: tokens += h2; token write; optional next-depth LN*wpt -> rbuf ----
    float sum2 = 0.f, sq2 = 0.f;
    if (tout_nc){
        float* tn = tdst + ((((size_t)(b << 15)) + p0 + p) << 8) + c0;
        #pragma unroll
        for (int j = 0; j < 4; ++j){
            ushort8v u = *(const ushort8v*)(hrow + 8*j);
            floatx4 fa, fb;
            #pragma unroll
            for (int e = 0; e < 4; ++e){
                int k = j*8 + e;
                float v = vreg[k] + b2f(u[e]);
                vreg[k] = v; fa[e] = v; sum2 += v; sq2 += v*v;
            }
            #pragma unroll
            for (int e = 4; e < 8; ++e){
                int k = j*8 + e;
                float v = vreg[k] + b2f(u[e]);
                vreg[k] = v; fb[e-4] = v; sum2 += v; sq2 += v*v;
            }
            *(floatx4*)(tn + 8*j) = fa;
            *(floatx4*)(tn + 8*j + 4) = fb;
        }
    } else {
        float* ob = tdst + ((size_t)b << 8)*Nn + p0 + p;
        #pragma unroll
        for (int j = 0; j < 4; ++j){
            ushort8v u = *(const ushort8v*)(hrow + 8*j);
            #pragma unroll
            for (int e = 0; e < 8; ++e){
                int k = j*8 + e, c = c0 + k;
                float v = vreg[k] + b2f(u[e]);
                vreg[k] = v;
                ob[(size_t)c << 15] = v;
                sum2 += v; sq2 += v*v;
            }
        }
    }
    if (donext){
        reds[tid] = sum2; redq[tid] = sq2;
        __syncthreads();
        if (tid < 64){
            float s = 0.f, q = 0.f;
            #pragma unroll
            for (int j = 0; j < 8; ++j){ s += reds[j*64 + tid]; q += redq[j*64 + tid]; }
            float m = s * (1.f/256.f);
            float var = q * (1.f/256.f) - m*m;
            m_s[tid] = m;
            r_s[tid] = rsqrtf(fmaxf(var, 0.f) + 1e-5f);
        }
        __syncthreads();
        float m2 = m_s[p], rr2 = r_s[p];
        float wv2 = wptb[(b*3 + g2)*Nn + p0 + p];
        unsigned short* rb = rbufn + ((size_t)((b << 15) + p0 + p))*Cc + c0;
        #pragma unroll
        for (int j = 0; j < 4; ++j){
            ushort8v u;
            #pragma unroll
            for (int e = 0; e < 8; ++e){
                int k = j*8 + e, c = c0 + k;
                u[e] = f2h(((vreg[k] - m2)*rr2*g2g_s[c] + g2b_s[c]) * wv2);
            }
            *(ushort8v*)(rb + 8*j) = u;
        }
    }
}

extern "C" void kernel_launch(void* const* d_in, const int* in_sizes, int n_in,
                              void* d_out, int out_size, void* d_ws, size_t ws_size,
                              hipStream_t stream){
    (void)in_sizes; (void)n_in; (void)out_size;
    const float* tokens  = (const float*)d_in[0];
    const int*   cellind = (const int*)d_in[1];
    const float* occ     = (const float*)d_in[2];
    const float* smix_g  = (const float*)d_in[3];
    const float* smix_b  = (const float*)d_in[4];
    const float* ffn_w1  = (const float*)d_in[5];
    const float* ffn_b1  = (const float*)d_in[6];
    const float* ffn_w2  = (const float*)d_in[7];
    const float* ffn_b2  = (const float*)d_in[8];
    const float* att_sc  = (const float*)d_in[9];
    const float* bn_g    = (const float*)d_in[10];
    const float* bn_b    = (const float*)d_in[11];
    const float* cm_g    = (const float*)d_in[12];
    const float* cm_b    = (const float*)d_in[13];
    const float* cw1     = (const float*)d_in[14];
    const float* cb1     = (const float*)d_in[15];
    const float* cw2     = (const float*)d_in[16];
    const float* cb2     = (const float*)d_in[17];
    const float* cscale  = (const float*)d_in[18];
    float* out = (float*)d_out;
    char* w = (char*)d_ws;

    const size_t HGRID_BYTES = (size_t)Bb*Cc*HWc*2;          // 16777216
    unsigned short* grid_h  = (unsigned short*)(w);
    unsigned short* attp_h  = grid_h;                        // alias: grid dead after k2
    unsigned short* planeA  = (unsigned short*)(w + HGRID_BYTES);
    unsigned short* planeB  = (unsigned short*)(w + 2*HGRID_BYTES);
    unsigned short* rbuf    = (unsigned short*)(w + 3*HGRID_BYTES);  // [b][n][c] fp16, 33.5 MB
    size_t o = 3*HGRID_BYTES + (size_t)Bb*Nn*Cc*2;
    float* fcounts = (float*)(w + o); o += (size_t)Bb*3*HWc*4;
    int*   icounts = (int*)(w + o);   o += (size_t)Bb*3*HWc*4;
    float* wptb   = (float*)(w + o); o += (size_t)Bb*3*Nn*4;
    float* bnS    = (float*)(w + o);
    float* bnQ    = bnS + 256;
    o += 4096;
    unsigned short* W1b = (unsigned short*)(w + o);
    unsigned short* W2b = W1b + 4*Cc*Cc;
    o += (size_t)2*4*Cc*Cc*2;
    int* startsb  = (int*)(w + o); o += (size_t)Bb*3*(HWc+1)*4;
    int* cursors  = (int*)(w + o); o += (size_t)Bb*3*HWc*4;
    int* plistb   = (int*)(w + o); o += (size_t)Bb*3*Nn*4;
    o = (o + 255) & ~(size_t)255;
    float* tnc    = (float*)(w + o);                         // [b][n][c] fp32 intermediate, 64 MB
    size_t needed = o + (size_t)Bb*Nn*Cc*4;
    int nc_ok = (ws_size >= needed) ? 1 : 0;

    // ---- setup (once per launch) ----
    hipMemsetAsync(fcounts, 0, (size_t)2*Bb*3*HWc*4, stream);
    k_count<<<(Bb*3*Nn)/256, 256, 0, stream>>>(cellind, occ, fcounts, icounts);
    k_wpt<<<(Bb*3*Nn)/256, 256, 0, stream>>>(cellind, occ, fcounts, wptb);
    k_scan<<<Bb*3, 256, 0, stream>>>(icounts, startsb, cursors);
    k_fill<<<(Bb*3*Nn)/256, 256, 0, stream>>>(cellind, cursors, plistb);
    k_wcvt<<<(4*Cc*Cc)/256, 256, 0, stream>>>(cw1, cw2, W1b, W2b);

    // depth-0 rbuf from input tokens
    k1a_ln<<<Bb*(Nn/256), 256, 0, stream>>>(tokens, wptb, smix_g, smix_b, rbuf, 0);

    for (int d = 0; d < 4; ++d){
        int g = d % 3;
        int g2 = (d + 1) % 3;
        int donext = (d < 3) ? 1 : 0;
        int useskip = (d == 3) ? 1 : 0;
        unsigned short* plane = (d == 0) ? planeA : planeB;
        int dn = (d + 1 < 4) ? d + 1 : d;   // next depth params (unused when donext=0)

        const float* tsrc; int tin_nc;
        float* tdst; int tout_nc;
        if (nc_ok){
            tsrc = (d == 0) ? tokens : tnc;  tin_nc  = (d == 0) ? 0 : 1;
            tdst = (d == 3) ? out : tnc;     tout_nc = (d == 3) ? 0 : 1;
        } else {
            tsrc = (d == 0) ? tokens : out;  tin_nc  = 0;
            tdst = out;                      tout_nc = 0;
        }

        hipMemsetAsync(bnS, 0, 2048, stream);

        k1b_gather<<<Bb*(HWc/8), 256, 0, stream>>>(rbuf, startsb, plistb, grid_h, g);
        k2_conv<<<Bb*Cc*4, 256, 0, stream>>>(grid_h, planeA, plane,
                                             ffn_w1 + d*Cc*9, ffn_b1 + d*Cc,
                                             ffn_w2 + d*Cc*9, ffn_b2 + d*Cc,
                                             att_sc + d*Cc, bnS, bnQ, useskip);
        k3t_att_t<<<Bb*8*512, 256, 0, stream>>>(plane, bnS, bnQ, att_sc + d*Cc,
                                                bn_g + d*Cc, bn_b + d*Cc, attp_h);
        k4_cmix<<<Bb*(Nn/64), 512, 0, stream>>>(tsrc, tin_nc, tdst, tout_nc, attp_h, cellind,
                                                W1b + (size_t)d*Cc*Cc, W2b + (size_t)d*Cc*Cc,
                                                cm_g + d*Cc, cm_b + d*Cc,
                                                cb1 + d*Cc, cb2 + d*Cc, cscale + d*Cc,
                                                smix_g + dn*Cc, smix_b + dn*Cc, wptb,
                                                rbuf, g, g2, donext);
    }
}

// Round 8
// 702.853 us; speedup vs baseline: 1.3109x; 1.0771x over previous
//
#include <hip/hip_runtime.h>
#include <hip/hip_bf16.h>
#include <hip/hip_fp16.h>

#define Cc 256
#define Nn 32768
#define HWc 16384
#define Bb 2

typedef float floatx4 __attribute__((ext_vector_type(4)));
typedef short bf16x8 __attribute__((ext_vector_type(8)));
typedef unsigned short ushort8v __attribute__((ext_vector_type(8)));
typedef unsigned short ushort4v __attribute__((ext_vector_type(4)));

__device__ __forceinline__ unsigned short f2b(float f){
    unsigned u = __float_as_uint(f);
    u += 0x7fff + ((u >> 16) & 1);
    return (unsigned short)(u >> 16);
}
__device__ __forceinline__ float b2f(unsigned short h){
    return __uint_as_float(((unsigned)h) << 16);
}
__device__ __forceinline__ unsigned short f2h(float f){
    return __half_as_ushort(__float2half(f));
}
__device__ __forceinline__ float h2f(unsigned short h){
    return __half2float(__ushort_as_half(h));
}

// ---------------- setup kernels ----------------
__global__ __launch_bounds__(256) void k_count(const int* __restrict__ ci,
                                               const float* __restrict__ occ,
                                               float* __restrict__ fcounts,
                                               int* __restrict__ icounts){
    int idx = blockIdx.x*256 + threadIdx.x;
    if (idx >= Bb*3*Nn) return;
    int n = idx & (Nn-1);
    int bg = idx >> 15;           // b*3+g
    int b = bg / 3;
    int cell = min(max(ci[idx], 0), HWc-1);
    float o = occ[(b<<15) + n];
    atomicAdd(&fcounts[(bg<<14) + cell], o*o);
    atomicAdd(&icounts[(bg<<14) + cell], 1);
}

__global__ __launch_bounds__(256) void k_wpt(const int* __restrict__ ci,
                                             const float* __restrict__ occ,
                                             const float* __restrict__ fcounts,
                                             float* __restrict__ wpt){
    int idx = blockIdx.x*256 + threadIdx.x;
    if (idx >= Bb*3*Nn) return;
    int n = idx & (Nn-1);
    int bg = idx >> 15;
    int b = bg / 3;
    int cell = min(max(ci[idx], 0), HWc-1);
    float o = occ[(b<<15) + n];
    float cnt = fcounts[(bg<<14) + cell];
    wpt[idx] = o / (o*cnt + 1e-6f);
}

// exclusive prefix scan of per-cell int counts -> starts[HW+1], cursors copy
__global__ __launch_bounds__(256) void k_scan(const int* __restrict__ ic,
                                              int* __restrict__ starts,
                                              int* __restrict__ cursor){
    __shared__ int part[256];
    int bg = blockIdx.x;          // 0..5
    int t = threadIdx.x;
    const int* cs = ic + (bg << 14);
    int base = t * 64;
    int s = 0;
    for (int i = 0; i < 64; ++i) s += cs[base + i];
    part[t] = s;
    __syncthreads();
    for (int off = 1; off < 256; off <<= 1){
        int v = (t >= off) ? part[t - off] : 0;
        __syncthreads();
        part[t] += v;
        __syncthreads();
    }
    int run = (t == 0) ? 0 : part[t - 1];
    int* st = starts + bg * (HWc + 1);
    int* cu = cursor + (bg << 14);
    for (int i = 0; i < 64; ++i){
        st[base + i] = run;
        cu[base + i] = run;
        run += cs[base + i];
    }
    if (t == 255) st[HWc] = run;
}

__global__ __launch_bounds__(256) void k_fill(const int* __restrict__ ci,
                                              int* __restrict__ cursor,
                                              int* __restrict__ plist){
    int idx = blockIdx.x*256 + threadIdx.x;
    if (idx >= Bb*3*Nn) return;
    int n = idx & (Nn-1);
    int bg = idx >> 15;
    int cell = min(max(ci[idx], 0), HWc-1);
    int pos = atomicAdd(&cursor[(bg<<14) + cell], 1);
    plist[(bg<<15) + pos] = n;
}

__global__ __launch_bounds__(256) void k_wcvt(const float* __restrict__ w1,
                                              const float* __restrict__ w2,
                                              unsigned short* __restrict__ W1b,
                                              unsigned short* __restrict__ W2b){
    int idx = blockIdx.x*256 + threadIdx.x;
    if (idx >= 4*Cc*Cc) return;
    W1b[idx] = f2b(w1[idx]);
    W2b[idx] = f2b(w2[idx]);
}

// ---------------- K1a (depth 0 only): LayerNorm(smix) * wpt -> rbuf [b][n][c] fp16 ----------------
// Single-read restructure (k4-epilogue style): 512 threads, 64 points/block; thread (p,cg)
// holds 32 channels in vreg; LDS cross-group reduce. Tokens read ONCE (was twice).
__global__ __launch_bounds__(512, 4) void k1a_ln(const float* __restrict__ tok,
                                              const float* __restrict__ wpt,
                                              const float* __restrict__ lng,
                                              const float* __restrict__ lnb,
                                              unsigned short* __restrict__ rbuf, int g){
    __shared__ float reds[512], redq[512];
    __shared__ float m_s[64], r_s[64];
    __shared__ float lg[Cc], lb[Cc];
    int tid = threadIdx.x;
    int bi = blockIdx.x;                 // Bb * (Nn/64)
    int b = bi >> 9;
    int p0 = (bi & 511) << 6;
    if (tid < 256){ lg[tid] = lng[tid]; lb[tid] = lnb[tid]; }
    int p  = tid & 63;
    int cg = tid >> 6;
    int c0 = cg << 5;
    const float* tb = tok + ((size_t)b << 8)*Nn + p0 + p;
    float vreg[32];
    float sum = 0.f, sq = 0.f;
    #pragma unroll
    for (int k = 0; k < 32; ++k){
        float v = tb[(size_t)(c0 + k) << 15];
        vreg[k] = v; sum += v; sq += v*v;
    }
    reds[tid] = sum; redq[tid] = sq;
    __syncthreads();
    if (tid < 64){
        float s = 0.f, q = 0.f;
        #pragma unroll
        for (int j = 0; j < 8; ++j){ s += reds[j*64 + tid]; q += redq[j*64 + tid]; }
        float m = s * (1.f/256.f);
        float var = q * (1.f/256.f) - m*m;
        m_s[tid] = m;
        r_s[tid] = rsqrtf(fmaxf(var, 0.f) + 1e-5f);
    }
    __syncthreads();
    float mp = m_s[p], rp = r_s[p];
    float wv = wpt[(b*3 + g)*Nn + p0 + p];
    unsigned short* rb = rbuf + ((size_t)((b << 15) + p0 + p))*Cc + c0;
    #pragma unroll
    for (int j = 0; j < 4; ++j){
        ushort8v u;
        #pragma unroll
        for (int e = 0; e < 8; ++e){
            int k = j*8 + e, c = c0 + k;
            u[e] = f2h(((vreg[k] - mp)*rp*lg[c] + lb[c]) * wv);
        }
        *(ushort8v*)(rb + 8*j) = u;
    }
}

// ---------------- K1b: CSR gather rbuf -> grid fp16 [b][c][hw], no atomics ----------------
// 8 cells/block. Block 0 also zeroes bnS/bnQ for this depth (replaces a memset dispatch;
// k1b runs strictly before k2 and after the previous depth's k3t consumed bnS).
__global__ __launch_bounds__(256) void k1b_gather(const unsigned short* __restrict__ rbuf,
                                                  const int* __restrict__ starts,
                                                  const int* __restrict__ plist,
                                                  unsigned short* __restrict__ grid,
                                                  float* __restrict__ bnSQ, int g){
    int t = threadIdx.x;                   // channel
    int bi = blockIdx.x;                   // Bb * (HW/8)
    if (bi == 0){ bnSQ[t] = 0.f; bnSQ[256 + t] = 0.f; }
    int b = bi >> 11;
    int cell0 = (bi & 2047) << 3;
    int bg = b*3 + g;
    const int* st = starts + bg*(HWc + 1) + cell0;
    const int* pl = plist + (bg << 15);
    const unsigned short* rb = rbuf + (((size_t)b << 15) << 8);
    float acc[8];
    int s0 = st[0];
    #pragma unroll
    for (int q = 0; q < 8; ++q){
        int s1 = st[q + 1];
        float a = 0.f;
        for (int j = s0; j < s1; ++j){
            int p = pl[j];
            a += h2f(rb[((size_t)p << 8) + t]);
        }
        acc[q] = a;
        s0 = s1;
    }
    unsigned short* go = grid + ((size_t)((b << 8) + t))*HWc + cell0;
    ushort8v u;
    #pragma unroll
    for (int e = 0; e < 8; ++e) u[e] = f2h(acc[e]);
    *(ushort8v*)go = u;
}

// ---------------- K2: fused dwconv3 -> relu -> dwconv3 (+skip) + BN partial sums (fp16 IO) ------
// Conv phases process 4 px/thread with vector LDS reads (1 b128 + 2 b32 per tap-row)
// instead of 9 scalar ds_read per px. Rows padded to 136 floats so tail vector reads stay
// in-bounds; out-of-image validity via select (no NaN from uninit LDS).
__global__ __launch_bounds__(256) void k2_conv(const unsigned short* __restrict__ grid,
                                               const unsigned short* __restrict__ skip,
                                               unsigned short* __restrict__ plane,
                                               const float* __restrict__ w1, const float* __restrict__ b1,
                                               const float* __restrict__ w2, const float* __restrict__ b2,
                                               const float* __restrict__ asc,
                                               float* __restrict__ bnS, float* __restrict__ bnQ,
                                               int useskip){
    __shared__ float it[36*136];
    __shared__ float mid[34*136];
    int tid = threadIdx.x;
    int bi = blockIdx.x;
    int rt = bi & 3;
    int bc = bi >> 2;              // b*256+c
    int c = bc & 255;
    int r0 = rt << 5;
    const unsigned short* src = grid + (size_t)bc*HWc;
    const unsigned short* sk  = skip + (size_t)bc*HWc;
    // zero halo columns (and the 2 tail cols vector reads can touch)
    for (int i = tid; i < 36; i += 256){
        it[i*136 + 0] = 0.f;   it[i*136 + 1] = 0.f;
        it[i*136 + 130] = 0.f; it[i*136 + 131] = 0.f;
        it[i*136 + 132] = 0.f; it[i*136 + 133] = 0.f;
    }
    // interior: 36 rows x 16 chunks of 8 px (vector loads)
    for (int i = tid; i < 36*16; i += 256){
        int r = i >> 4, ch = i & 15;
        int gy = r0 - 2 + r;
        float vals[8];
        #pragma unroll
        for (int e = 0; e < 8; ++e) vals[e] = 0.f;
        if ((unsigned)gy < 128u){
            ushort8v sv = *(const ushort8v*)(src + (gy << 7) + ch*8);
            if (useskip){
                ushort8v kv = *(const ushort8v*)(sk + (gy << 7) + ch*8);
                #pragma unroll
                for (int e = 0; e < 8; ++e) vals[e] = h2f(sv[e]) + h2f(kv[e]);
            } else {
                #pragma unroll
                for (int e = 0; e < 8; ++e) vals[e] = h2f(sv[e]);
            }
        }
        #pragma unroll
        for (int e = 0; e < 8; ++e) it[r*136 + 2 + ch*8 + e] = vals[e];
    }
    float a1[9], a2[9];
    #pragma unroll
    for (int j = 0; j < 9; ++j){ a1[j] = w1[c*9+j]; a2[j] = w2[c*9+j]; }
    float bb1 = b1[c], bb2 = b2[c], sc = asc[c];
    __syncthreads();
    // conv1 -> mid: 34 rows x 33 chunks of 4
    for (int i = tid; i < 34*33; i += 256){
        int r = i / 33, chk = i - r*33;
        int cc0 = chk << 2;
        int y = r0 - 1 + r;
        bool yok = (unsigned)y < 128u;
        float o0 = 0.f, o1 = 0.f, o2 = 0.f, o3 = 0.f;
        if (yok){
            #pragma unroll
            for (int jr = 0; jr < 3; ++jr){
                const float* row = &it[(r + jr)*136 + cc0];
                floatx4 a = *(const floatx4*)row;
                float a4 = row[4], a5 = row[5];
                float w0 = a1[jr*3+0], w1v = a1[jr*3+1], w2v = a1[jr*3+2];
                o0 += w0*a[0] + w1v*a[1] + w2v*a[2];
                o1 += w0*a[1] + w1v*a[2] + w2v*a[3];
                o2 += w0*a[2] + w1v*a[3] + w2v*a4;
                o3 += w0*a[3] + w1v*a4  + w2v*a5;
            }
        }
        float* mrow = &mid[r*136 + cc0];
        mrow[0] = (yok && cc0+0 >= 1 && cc0+0 <= 128) ? fmaxf(o0 + bb1, 0.f) : 0.f;
        mrow[1] = (yok && cc0+1 >= 1 && cc0+1 <= 128) ? fmaxf(o1 + bb1, 0.f) : 0.f;
        mrow[2] = (yok && cc0+2 >= 1 && cc0+2 <= 128) ? fmaxf(o2 + bb1, 0.f) : 0.f;
        mrow[3] = (yok && cc0+3 >= 1 && cc0+3 <= 128) ? fmaxf(o3 + bb1, 0.f) : 0.f;
    }
    __syncthreads();
    float ps = 0.f, pq = 0.f;
    unsigned short* dst = plane + (size_t)bc*HWc;
    // conv2 -> out: 32 rows x 32 chunks of 4 px (vector stores)
    for (int i = tid; i < 32*32; i += 256){
        int yy = i >> 5, chk = i & 31;
        int x0 = chk << 2;
        float o0 = 0.f, o1 = 0.f, o2 = 0.f, o3 = 0.f;
        #pragma unroll
        for (int jr = 0; jr < 3; ++jr){
            const float* row = &mid[(yy + jr)*136 + x0];
            floatx4 a = *(const floatx4*)row;
            float a4 = row[4], a5 = row[5];
            float w0 = a2[jr*3+0], w1v = a2[jr*3+1], w2v = a2[jr*3+2];
            o0 += w0*a[0] + w1v*a[1] + w2v*a[2];
            o1 += w0*a[1] + w1v*a[2] + w2v*a[3];
            o2 += w0*a[2] + w1v*a[3] + w2v*a4;
            o3 += w0*a[3] + w1v*a4  + w2v*a5;
        }
        float v0 = o0 + bb2, v1 = o1 + bb2, v2 = o2 + bb2, v3 = o3 + bb2;
        ushort4v u;
        u[0] = f2h(v0); u[1] = f2h(v1); u[2] = f2h(v2); u[3] = f2h(v3);
        *(ushort4v*)(dst + ((r0 + yy) << 7) + x0) = u;
        float t0 = v0*sc, t1 = v1*sc, t2 = v2*sc, t3 = v3*sc;
        ps += t0 + t1 + t2 + t3;
        pq += t0*t0 + t1*t1 + t2*t2 + t3*t3;
    }
    __syncthreads();
    it[tid] = ps; it[256 + tid] = pq;
    __syncthreads();
    for (int s2 = 128; s2 > 0; s2 >>= 1){
        if (tid < s2){ it[tid] += it[tid+s2]; it[256+tid] += it[256+tid+s2]; }
        __syncthreads();
    }
    if (tid == 0){
        atomicAdd(&bnS[c], it[0]);
        atomicAdd(&bnQ[c], it[256]);
    }
}

// ---------------- K3t: BN fold + sigmoid gate + transpose plane -> attp fp16 [b][hw][c] ----------
__global__ __launch_bounds__(256) void k3t_att_t(const unsigned short* __restrict__ plane,
                                                 const float* __restrict__ bnS, const float* __restrict__ bnQ,
                                                 const float* __restrict__ asc,
                                                 const float* __restrict__ bng, const float* __restrict__ bnb,
                                                 unsigned short* __restrict__ attp){
    __shared__ float t[32*33];
    __shared__ float P_s[32], Q_s[32];
    int tid = threadIdx.x;
    int tx = tid & 31, ty = tid >> 5;
    int bi = blockIdx.x;
    int ht = bi & 511;
    int ct = (bi >> 9) & 7;
    int b  = bi >> 12;
    int c0 = ct << 5, h0 = ht << 5;
    if (tid < 32){
        int c = c0 + tid;
        float mean = bnS[c] * (1.f/32768.f);
        float var  = bnQ[c] * (1.f/32768.f) - mean*mean;
        float inv  = rsqrtf(fmaxf(var, 0.f) + 1e-5f) * bng[c];
        P_s[tid] = asc[c] * inv;
        Q_s[tid] = bnb[c] - mean * inv;
    }
    __syncthreads();
    for (int r = ty; r < 32; r += 8){
        int c = c0 + r;
        float v = h2f(plane[(((size_t)b << 8) + c)*HWc + h0 + tx]);
        float s = 1.f / (1.f + __expf(-(P_s[r]*v + Q_s[r])));
        t[r*33 + tx] = s * v;
    }
    __syncthreads();
    for (int r = ty; r < 32; r += 8){
        attp[(((size_t)b << 14) + h0 + r)*Cc + c0 + tx] = f2h(t[tx*33 + r]);
    }
}

// ---------------- K4: gather + cmix LN + MFMA mm1(relu) + mm2 + residual + next-depth LN ----------
// 512 threads = 8 waves, 64 points/block (Round-1/5 structure, best measured: 82 us).
// NOTE (R6 lesson): working set needs ~92-100 unified regs; forcing 6 waves/SIMD via
// launch_bounds spills to scratch (+80MB HBM, 140us). Do not raise the wave bound.
__global__ __launch_bounds__(512, 4) void k4_cmix(const float* __restrict__ tsrc, int tin_nc,
                                               float* __restrict__ tdst, int tout_nc,
                                               const unsigned short* __restrict__ attp,  // fp16 [b][hw][c]
                                               const int* __restrict__ ci,
                                               const unsigned short* __restrict__ W1,
                                               const unsigned short* __restrict__ W2,
                                               const float* __restrict__ lng, const float* __restrict__ lnb,
                                               const float* __restrict__ b1, const float* __restrict__ b2,
                                               const float* __restrict__ csc,
                                               const float* __restrict__ lng2, const float* __restrict__ lnb2,
                                               const float* __restrict__ wptb,
                                               unsigned short* __restrict__ rbufn,      // fp16 [b][n][c]
                                               int g, int g2, int donext){
    __shared__ __align__(16) unsigned short hs[64*264];    // 33792 B: h -> h1 -> h2
    __shared__ float reds[512], redq[512];
    __shared__ float m_s[64], r_s[64];
    __shared__ int cell_s[64];
    __shared__ float lng_s[Cc], lnb_s[Cc], b1_s[Cc], b2s_s[Cc], cs_s[Cc], g2g_s[Cc], g2b_s[Cc];

    int tid = threadIdx.x;
    int bi = blockIdx.x;
    int b = bi >> 9;               // 512 blocks per batch, 64 points each
    int p0 = (bi & 511) << 6;

    if (tid < 256){
        lng_s[tid] = lng[tid];
        lnb_s[tid] = lnb[tid];
        b1_s[tid]  = b1[tid];
        float cv = csc[tid];
        cs_s[tid]  = cv;
        b2s_s[tid] = b2[tid] * cv;
        g2g_s[tid] = lng2[tid];
        g2b_s[tid] = lnb2[tid];
    }
    if (tid < 64){
        int cc = ci[(b*3 + g)*Nn + p0 + tid];
        cell_s[tid] = min(max(cc, 0), HWc-1);
    }
    __syncthreads();

    int p  = tid & 63;
    int cg = tid >> 6;
    int c0 = cg << 5;

    // ---- direct register gather: tokens + attp row chunk (4x16B) ----
    const unsigned short* ar = attp + ((size_t)((b << 14) + cell_s[p]))*Cc + c0;
    ushort8v rr[4];
    #pragma unroll
    for (int j = 0; j < 4; ++j) rr[j] = *(const ushort8v*)(ar + 8*j);

    float vreg[32];
    float sum = 0.f, sq = 0.f;
    if (tin_nc){
        const floatx4* tn4 = (const floatx4*)(tsrc + ((((size_t)(b << 15)) + p0 + p) << 8) + c0);
        #pragma unroll
        for (int j = 0; j < 8; ++j){
            floatx4 f = tn4[j];
            #pragma unroll
            for (int e = 0; e < 4; ++e){
                int k = j*4 + e;
                float v = f[e] + h2f(rr[k >> 3][k & 7]);
                vreg[k] = v; sum += v; sq += v*v;
            }
        }
    } else {
        const float* tb = tsrc + ((size_t)b << 8)*Nn + p0 + p;
        #pragma unroll
        for (int k = 0; k < 32; ++k){
            float v = tb[(size_t)(c0 + k) << 15] + h2f(rr[k >> 3][k & 7]);
            vreg[k] = v; sum += v; sq += v*v;
        }
    }
    reds[tid] = sum; redq[tid] = sq;
    __syncthreads();
    if (tid < 64){
        float s = 0.f, q = 0.f;
        #pragma unroll
        for (int j = 0; j < 8; ++j){ s += reds[j*64 + tid]; q += redq[j*64 + tid]; }
        float m = s * (1.f/256.f);
        float var = q * (1.f/256.f) - m*m;
        m_s[tid] = m;
        r_s[tid] = rsqrtf(fmaxf(var, 0.f) + 1e-5f);
    }
    __syncthreads();
    float mp = m_s[p], rp = r_s[p];
    unsigned short* hrow = &hs[p*264 + c0];
    #pragma unroll
    for (int j = 0; j < 4; ++j){
        ushort8v u;
        #pragma unroll
        for (int e = 0; e < 8; ++e){
            int k = j*8 + e, c = c0 + k;
            u[e] = f2b((vreg[k] - mp)*rp*lng_s[c] + lnb_s[c]);
        }
        *(ushort8v*)(hrow + 8*j) = u;
    }
    __syncthreads();

    int lane = tid & 63;
    int w = tid >> 6;              // wave index 0..7 -> output channels w*32..w*32+31
    int l15 = lane & 15;
    int q4 = lane >> 4;
    floatx4 acc[2][4];
    #pragma unroll
    for (int mi = 0; mi < 2; ++mi)
        #pragma unroll
        for (int ni = 0; ni < 4; ++ni)
            acc[mi][ni] = (floatx4){0.f, 0.f, 0.f, 0.f};

    // mm1: h1 = relu(W1 @ h + b1)
    #pragma unroll
    for (int kk = 0; kk < 8; ++kk){
        int k0 = kk*32 + q4*8;
        bf16x8 bfr[4];
        #pragma unroll
        for (int ni = 0; ni < 4; ++ni)
            bfr[ni] = *(const bf16x8*)&hs[(ni*16 + l15)*264 + k0];
        #pragma unroll
        for (int mi = 0; mi < 2; ++mi){
            bf16x8 af = *(const bf16x8*)&W1[(size_t)(w*32 + mi*16 + l15)*Cc + k0];
            #pragma unroll
            for (int ni = 0; ni < 4; ++ni)
                acc[mi][ni] = __builtin_amdgcn_mfma_f32_16x16x32_bf16(af, bfr[ni], acc[mi][ni], 0, 0, 0);
        }
    }
    __syncthreads();   // all h reads done
    #pragma unroll
    for (int mi = 0; mi < 2; ++mi)
        #pragma unroll
        for (int ni = 0; ni < 4; ++ni){
            int m0 = w*32 + mi*16 + q4*4;
            int nn = ni*16 + l15;
            ushort4v u;
            #pragma unroll
            for (int r = 0; r < 4; ++r)
                u[r] = f2b(fmaxf(acc[mi][ni][r] + b1_s[m0 + r], 0.f));
            *(ushort4v*)&hs[nn*264 + m0] = u;   // h1 [point][channel]
        }
    __syncthreads();

    // mm2: h2 = (W2 @ h1)*cs + b2*cs
    #pragma unroll
    for (int mi = 0; mi < 2; ++mi)
        #pragma unroll
        for (int ni = 0; ni < 4; ++ni)
            acc[mi][ni] = (floatx4){0.f, 0.f, 0.f, 0.f};
    #pragma unroll
    for (int kk = 0; kk < 8; ++kk){
        int k0 = kk*32 + q4*8;
        bf16x8 bfr[4];
        #pragma unroll
        for (int ni = 0; ni < 4; ++ni)
            bfr[ni] = *(const bf16x8*)&hs[(ni*16 + l15)*264 + k0];
        #pragma unroll
        for (int mi = 0; mi < 2; ++mi){
            bf16x8 af = *(const bf16x8*)&W2[(size_t)(w*32 + mi*16 + l15)*Cc + k0];
            #pragma unroll
            for (int ni = 0; ni < 4; ++ni)
                acc[mi][ni] = __builtin_amdgcn_mfma_f32_16x16x32_bf16(af, bfr[ni], acc[mi][ni], 0, 0, 0);
        }
    }
    __syncthreads();   // all h1 reads done
    #pragma unroll
    for (int mi = 0; mi < 2; ++mi)
        #pragma unroll
        for (int ni = 0; ni < 4; ++ni){
            int m0 = w*32 + mi*16 + q4*4;
            int nn = ni*16 + l15;
            ushort4v u;
            #pragma unroll
            for (int r = 0; r < 4; ++r)
                u[r] = f2b(acc[mi][ni][r]*cs_s[m0 + r] + b2s_s[m0 + r]);
            *(ushort4v*)&hs[nn*264 + m0] = u;   // h2 [point][channel]
        }
    __syncthreads();

    // ---- epilogue: tokens += h2; token write; optional next-depth LN*wpt -> rbuf ----
    float sum2 = 0.f, sq2 = 0.f;
    if (tout_nc){
        float* tn = tdst + ((((size_t)(b << 15)) + p0 + p) << 8) + c0;
        #pragma unroll
        for (int j = 0; j < 4; ++j){
            ushort8v u = *(const ushort8v*)(hrow + 8*j);
            floatx4 fa, fb;
            #pragma unroll
            for (int e = 0; e < 4; ++e){
                int k = j*8 + e;
                float v = vreg[k] + b2f(u[e]);
                vreg[k] = v; fa[e] = v; sum2 += v; sq2 += v*v;
            }
            #pragma unroll
            for (int e = 4; e < 8; ++e){
                int k = j*8 + e;
                float v = vreg[k] + b2f(u[e]);
                vreg[k] = v; fb[e-4] = v; sum2 += v; sq2 += v*v;
            }
            *(floatx4*)(tn + 8*j) = fa;
            *(floatx4*)(tn + 8*j + 4) = fb;
        }
    } else {
        float* ob = tdst + ((size_t)b << 8)*Nn + p0 + p;
        #pragma unroll
        for (int j = 0; j < 4; ++j){
            ushort8v u = *(const ushort8v*)(hrow + 8*j);
            #pragma unroll
            for (int e = 0; e < 8; ++e){
                int k = j*8 + e, c = c0 + k;
                float v = vreg[k] + b2f(u[e]);
                vreg[k] = v;
                ob[(size_t)c << 15] = v;
                sum2 += v; sq2 += v*v;
            }
        }
    }
    if (donext){
        reds[tid] = sum2; redq[tid] = sq2;
        __syncthreads();
        if (tid < 64){
            float s = 0.f, q = 0.f;
            #pragma unroll
            for (int j = 0; j < 8; ++j){ s += reds[j*64 + tid]; q += redq[j*64 + tid]; }
            float m = s * (1.f/256.f);
            float var = q * (1.f/256.f) - m*m;
            m_s[tid] = m;
            r_s[tid] = rsqrtf(fmaxf(var, 0.f) + 1e-5f);
        }
        __syncthreads();
        float m2 = m_s[p], rr2 = r_s[p];
        float wv2 = wptb[(b*3 + g2)*Nn + p0 + p];
        unsigned short* rb = rbufn + ((size_t)((b << 15) + p0 + p))*Cc + c0;
        #pragma unroll
        for (int j = 0; j < 4; ++j){
            ushort8v u;
            #pragma unroll
            for (int e = 0; e < 8; ++e){
                int k = j*8 + e, c = c0 + k;
                u[e] = f2h(((vreg[k] - m2)*rr2*g2g_s[c] + g2b_s[c]) * wv2);
            }
            *(ushort8v*)(rb + 8*j) = u;
        }
    }
}

extern "C" void kernel_launch(void* const* d_in, const int* in_sizes, int n_in,
                              void* d_out, int out_size, void* d_ws, size_t ws_size,
                              hipStream_t stream){
    (void)in_sizes; (void)n_in; (void)out_size;
    const float* tokens  = (const float*)d_in[0];
    const int*   cellind = (const int*)d_in[1];
    const float* occ     = (const float*)d_in[2];
    const float* smix_g  = (const float*)d_in[3];
    const float* smix_b  = (const float*)d_in[4];
    const float* ffn_w1  = (const float*)d_in[5];
    const float* ffn_b1  = (const float*)d_in[6];
    const float* ffn_w2  = (const float*)d_in[7];
    const float* ffn_b2  = (const float*)d_in[8];
    const float* att_sc  = (const float*)d_in[9];
    const float* bn_g    = (const float*)d_in[10];
    const float* bn_b    = (const float*)d_in[11];
    const float* cm_g    = (const float*)d_in[12];
    const float* cm_b    = (const float*)d_in[13];
    const float* cw1     = (const float*)d_in[14];
    const float* cb1     = (const float*)d_in[15];
    const float* cw2     = (const float*)d_in[16];
    const float* cb2     = (const float*)d_in[17];
    const float* cscale  = (const float*)d_in[18];
    float* out = (float*)d_out;
    char* w = (char*)d_ws;

    const size_t HGRID_BYTES = (size_t)Bb*Cc*HWc*2;          // 16777216
    unsigned short* grid_h  = (unsigned short*)(w);
    unsigned short* attp_h  = grid_h;                        // alias: grid dead after k2
    unsigned short* planeA  = (unsigned short*)(w + HGRID_BYTES);
    unsigned short* planeB  = (unsigned short*)(w + 2*HGRID_BYTES);
    unsigned short* rbuf    = (unsigned short*)(w + 3*HGRID_BYTES);  // [b][n][c] fp16, 33.5 MB
    size_t o = 3*HGRID_BYTES + (size_t)Bb*Nn*Cc*2;
    float* fcounts = (float*)(w + o); o += (size_t)Bb*3*HWc*4;
    int*   icounts = (int*)(w + o);   o += (size_t)Bb*3*HWc*4;
    float* wptb   = (float*)(w + o); o += (size_t)Bb*3*Nn*4;
    float* bnS    = (float*)(w + o);
    float* bnQ    = bnS + 256;
    o += 4096;
    unsigned short* W1b = (unsigned short*)(w + o);
    unsigned short* W2b = W1b + 4*Cc*Cc;
    o += (size_t)2*4*Cc*Cc*2;
    int* startsb  = (int*)(w + o); o += (size_t)Bb*3*(HWc+1)*4;
    int* cursors  = (int*)(w + o); o += (size_t)Bb*3*HWc*4;
    int* plistb   = (int*)(w + o); o += (size_t)Bb*3*Nn*4;
    o = (o + 255) & ~(size_t)255;
    float* tnc    = (float*)(w + o);                         // [b][n][c] fp32 intermediate, 64 MB
    size_t needed = o + (size_t)Bb*Nn*Cc*4;
    int nc_ok = (ws_size >= needed) ? 1 : 0;

    // ---- setup (once per launch) ----
    hipMemsetAsync(fcounts, 0, (size_t)2*Bb*3*HWc*4, stream);
    k_count<<<(Bb*3*Nn)/256, 256, 0, stream>>>(cellind, occ, fcounts, icounts);
    k_wpt<<<(Bb*3*Nn)/256, 256, 0, stream>>>(cellind, occ, fcounts, wptb);
    k_scan<<<Bb*3, 256, 0, stream>>>(icounts, startsb, cursors);
    k_fill<<<(Bb*3*Nn)/256, 256, 0, stream>>>(cellind, cursors, plistb);
    k_wcvt<<<(4*Cc*Cc)/256, 256, 0, stream>>>(cw1, cw2, W1b, W2b);

    // depth-0 rbuf from input tokens (single-read 512-thread version)
    k1a_ln<<<Bb*(Nn/64), 512, 0, stream>>>(tokens, wptb, smix_g, smix_b, rbuf, 0);

    for (int d = 0; d < 4; ++d){
        int g = d % 3;
        int g2 = (d + 1) % 3;
        int donext = (d < 3) ? 1 : 0;
        int useskip = (d == 3) ? 1 : 0;
        unsigned short* plane = (d == 0) ? planeA : planeB;
        int dn = (d + 1 < 4) ? d + 1 : d;   // next depth params (unused when donext=0)

        const float* tsrc; int tin_nc;
        float* tdst; int tout_nc;
        if (nc_ok){
            tsrc = (d == 0) ? tokens : tnc;  tin_nc  = (d == 0) ? 0 : 1;
            tdst = (d == 3) ? out : tnc;     tout_nc = (d == 3) ? 0 : 1;
        } else {
            tsrc = (d == 0) ? tokens : out;  tin_nc  = 0;
            tdst = out;                      tout_nc = 0;
        }

        // bnS/bnQ zeroed inside k1b block 0 (runs before k2, after prior k3t consumed them)
        k1b_gather<<<Bb*(HWc/8), 256, 0, stream>>>(rbuf, startsb, plistb, grid_h, bnS, g);
        k2_conv<<<Bb*Cc*4, 256, 0, stream>>>(grid_h, planeA, plane,
                                             ffn_w1 + d*Cc*9, ffn_b1 + d*Cc,
                                             ffn_w2 + d*Cc*9, ffn_b2 + d*Cc,
                                             att_sc + d*Cc, bnS, bnQ, useskip);
        k3t_att_t<<<Bb*8*512, 256, 0, stream>>>(plane, bnS, bnQ, att_sc + d*Cc,
                                                bn_g + d*Cc, bn_b + d*Cc, attp_h);
        k4_cmix<<<Bb*(Nn/64), 512, 0, stream>>>(tsrc, tin_nc, tdst, tout_nc, attp_h, cellind,
                                                W1b + (size_t)d*Cc*Cc, W2b + (size_t)d*Cc*Cc,
                                                cm_g + d*Cc, cm_b + d*Cc,
                                                cb1 + d*Cc, cb2 + d*Cc, cscale + d*Cc,
                                                smix_g + dn*Cc, smix_b + dn*Cc, wptb,
                                                rbuf, g, g2, donext);
    }
}

// Round 9
// 689.982 us; speedup vs baseline: 1.3354x; 1.0187x over previous
//
#include <hip/hip_runtime.h>
#include <hip/hip_bf16.h>
#include <hip/hip_fp16.h>

#define Cc 256
#define Nn 32768
#define HWc 16384
#define Bb 2
#define STS (HWc + 16)

typedef float floatx4 __attribute__((ext_vector_type(4)));
typedef short bf16x8 __attribute__((ext_vector_type(8)));
typedef unsigned short ushort8v __attribute__((ext_vector_type(8)));
typedef unsigned short ushort4v __attribute__((ext_vector_type(4)));
typedef int int4v __attribute__((ext_vector_type(4)));

__device__ __forceinline__ unsigned short f2b(float f){
    unsigned u = __float_as_uint(f);
    u += 0x7fff + ((u >> 16) & 1);
    return (unsigned short)(u >> 16);
}
__device__ __forceinline__ float b2f(unsigned short h){
    return __uint_as_float(((unsigned)h) << 16);
}
__device__ __forceinline__ unsigned short f2h(float f){
    return __half_as_ushort(__float2half(f));
}
__device__ __forceinline__ float h2f(unsigned short h){
    return __half2float(__ushort_as_half(h));
}

// ---------------- setup kernels ----------------
__global__ __launch_bounds__(256) void k_count(const int* __restrict__ ci,
                                               const float* __restrict__ occ,
                                               float* __restrict__ fcounts,
                                               int* __restrict__ icounts){
    int idx = blockIdx.x*256 + threadIdx.x;
    if (idx >= Bb*3*Nn) return;
    int n = idx & (Nn-1);
    int bg = idx >> 15;           // b*3+g
    int b = bg / 3;
    int cell = min(max(ci[idx], 0), HWc-1);
    float o = occ[(b<<15) + n];
    atomicAdd(&fcounts[(bg<<14) + cell], o*o);
    atomicAdd(&icounts[(bg<<14) + cell], 1);
}

// exclusive prefix scan of per-cell int counts -> starts[stride STS], cursors copy (int4)
__global__ __launch_bounds__(256) void k_scan(const int* __restrict__ ic,
                                              int* __restrict__ starts,
                                              int* __restrict__ cursor){
    __shared__ int part[256];
    int bg = blockIdx.x;          // 0..5
    int t = threadIdx.x;
    const int* cs = ic + (bg << 14);
    int4v buf[16];
    int s = 0;
    #pragma unroll
    for (int i = 0; i < 16; ++i){
        buf[i] = *(const int4v*)(cs + t*64 + i*4);
        s += buf[i][0] + buf[i][1] + buf[i][2] + buf[i][3];
    }
    part[t] = s;
    __syncthreads();
    for (int off = 1; off < 256; off <<= 1){
        int v = (t >= off) ? part[t - off] : 0;
        __syncthreads();
        part[t] += v;
        __syncthreads();
    }
    int run = (t == 0) ? 0 : part[t - 1];
    int* st = starts + bg * STS;
    int* cu = cursor + (bg << 14);
    #pragma unroll
    for (int i = 0; i < 16; ++i){
        int4v o;
        #pragma unroll
        for (int e = 0; e < 4; ++e){ o[e] = run; run += buf[i][e]; }
        *(int4v*)(st + t*64 + i*4) = o;
        *(int4v*)(cu + t*64 + i*4) = o;
    }
    if (t == 255) st[HWc] = run;
}

// fused: per-point weight (was k_wpt) + CSR fill
__global__ __launch_bounds__(256) void k_fill(const int* __restrict__ ci,
                                              const float* __restrict__ occ,
                                              const float* __restrict__ fcounts,
                                              int* __restrict__ cursor,
                                              int* __restrict__ plist,
                                              float* __restrict__ wpt){
    int idx = blockIdx.x*256 + threadIdx.x;
    if (idx >= Bb*3*Nn) return;
    int n = idx & (Nn-1);
    int bg = idx >> 15;
    int b = bg / 3;
    int cell = min(max(ci[idx], 0), HWc-1);
    float o = occ[(b<<15) + n];
    float cnt = fcounts[(bg<<14) + cell];
    wpt[idx] = o / (o*cnt + 1e-6f);
    int pos = atomicAdd(&cursor[(bg<<14) + cell], 1);
    plist[(bg<<15) + pos] = n;
}

__global__ __launch_bounds__(256) void k_wcvt(const float* __restrict__ w1,
                                              const float* __restrict__ w2,
                                              unsigned short* __restrict__ W1b,
                                              unsigned short* __restrict__ W2b){
    int idx = blockIdx.x*256 + threadIdx.x;
    if (idx >= 4*Cc*Cc) return;
    W1b[idx] = f2b(w1[idx]);
    W2b[idx] = f2b(w2[idx]);
}

// ---------------- K1a (depth 0 only): LayerNorm(smix) * wpt -> rbuf [b][n][c] fp16 ----------------
__global__ __launch_bounds__(512, 4) void k1a_ln(const float* __restrict__ tok,
                                              const float* __restrict__ wpt,
                                              const float* __restrict__ lng,
                                              const float* __restrict__ lnb,
                                              unsigned short* __restrict__ rbuf, int g){
    __shared__ float reds[512], redq[512];
    __shared__ float m_s[64], r_s[64];
    __shared__ float lg[Cc], lb[Cc];
    int tid = threadIdx.x;
    int bi = blockIdx.x;                 // Bb * (Nn/64)
    int b = bi >> 9;
    int p0 = (bi & 511) << 6;
    if (tid < 256){ lg[tid] = lng[tid]; lb[tid] = lnb[tid]; }
    int p  = tid & 63;
    int cg = tid >> 6;
    int c0 = cg << 5;
    const float* tb = tok + ((size_t)b << 8)*Nn + p0 + p;
    float vreg[32];
    float sum = 0.f, sq = 0.f;
    #pragma unroll
    for (int k = 0; k < 32; ++k){
        float v = tb[(size_t)(c0 + k) << 15];
        vreg[k] = v; sum += v; sq += v*v;
    }
    reds[tid] = sum; redq[tid] = sq;
    __syncthreads();
    if (tid < 64){
        float s = 0.f, q = 0.f;
        #pragma unroll
        for (int j = 0; j < 8; ++j){ s += reds[j*64 + tid]; q += redq[j*64 + tid]; }
        float m = s * (1.f/256.f);
        float var = q * (1.f/256.f) - m*m;
        m_s[tid] = m;
        r_s[tid] = rsqrtf(fmaxf(var, 0.f) + 1e-5f);
    }
    __syncthreads();
    float mp = m_s[p], rp = r_s[p];
    float wv = wpt[(b*3 + g)*Nn + p0 + p];
    unsigned short* rb = rbuf + ((size_t)((b << 15) + p0 + p))*Cc + c0;
    #pragma unroll
    for (int j = 0; j < 4; ++j){
        ushort8v u;
        #pragma unroll
        for (int e = 0; e < 8; ++e){
            int k = j*8 + e, c = c0 + k;
            u[e] = f2h(((vreg[k] - mp)*rp*lg[c] + lb[c]) * wv);
        }
        *(ushort8v*)(rb + 8*j) = u;
    }
}

// ---------------- K1b: CSR gather rbuf -> grid fp16 [b][c][hw], no atomics ----------------
__global__ __launch_bounds__(256) void k1b_gather(const unsigned short* __restrict__ rbuf,
                                                  const int* __restrict__ starts,
                                                  const int* __restrict__ plist,
                                                  unsigned short* __restrict__ grid,
                                                  float* __restrict__ bnSQ, int g){
    int t = threadIdx.x;                   // channel
    int bi = blockIdx.x;                   // Bb * (HW/8)
    if (bi == 0){ bnSQ[t] = 0.f; bnSQ[256 + t] = 0.f; }
    int b = bi >> 11;
    int cell0 = (bi & 2047) << 3;
    int bg = b*3 + g;
    const int* st = starts + bg*STS + cell0;
    const int* pl = plist + (bg << 15);
    const unsigned short* rb = rbuf + (((size_t)b << 15) << 8);
    float acc[8];
    int s0 = st[0];
    #pragma unroll
    for (int q = 0; q < 8; ++q){
        int s1 = st[q + 1];
        float a = 0.f;
        for (int j = s0; j < s1; ++j){
            int p = pl[j];
            a += h2f(rb[((size_t)p << 8) + t]);
        }
        acc[q] = a;
        s0 = s1;
    }
    unsigned short* go = grid + ((size_t)((b << 8) + t))*HWc + cell0;
    ushort8v u;
    #pragma unroll
    for (int e = 0; e < 8; ++e) u[e] = f2h(acc[e]);
    *(ushort8v*)go = u;
}

// ---------------- K2: fused dwconv3 -> relu -> dwconv3 (+skip) + BN partial sums (fp16 IO) ------
__global__ __launch_bounds__(256) void k2_conv(const unsigned short* __restrict__ grid,
                                               const unsigned short* __restrict__ skip,
                                               unsigned short* __restrict__ plane,
                                               const float* __restrict__ w1, const float* __restrict__ b1,
                                               const float* __restrict__ w2, const float* __restrict__ b2,
                                               const float* __restrict__ asc,
                                               float* __restrict__ bnS, float* __restrict__ bnQ,
                                               int useskip){
    __shared__ float it[36*136];
    __shared__ float mid[34*136];
    int tid = threadIdx.x;
    int bi = blockIdx.x;
    int rt = bi & 3;
    int bc = bi >> 2;              // b*256+c
    int c = bc & 255;
    int r0 = rt << 5;
    const unsigned short* src = grid + (size_t)bc*HWc;
    const unsigned short* sk  = skip + (size_t)bc*HWc;
    for (int i = tid; i < 36; i += 256){
        it[i*136 + 0] = 0.f;   it[i*136 + 1] = 0.f;
        it[i*136 + 130] = 0.f; it[i*136 + 131] = 0.f;
        it[i*136 + 132] = 0.f; it[i*136 + 133] = 0.f;
    }
    for (int i = tid; i < 36*16; i += 256){
        int r = i >> 4, ch = i & 15;
        int gy = r0 - 2 + r;
        float vals[8];
        #pragma unroll
        for (int e = 0; e < 8; ++e) vals[e] = 0.f;
        if ((unsigned)gy < 128u){
            ushort8v sv = *(const ushort8v*)(src + (gy << 7) + ch*8);
            if (useskip){
                ushort8v kv = *(const ushort8v*)(sk + (gy << 7) + ch*8);
                #pragma unroll
                for (int e = 0; e < 8; ++e) vals[e] = h2f(sv[e]) + h2f(kv[e]);
            } else {
                #pragma unroll
                for (int e = 0; e < 8; ++e) vals[e] = h2f(sv[e]);
            }
        }
        #pragma unroll
        for (int e = 0; e < 8; ++e) it[r*136 + 2 + ch*8 + e] = vals[e];
    }
    float a1[9], a2[9];
    #pragma unroll
    for (int j = 0; j < 9; ++j){ a1[j] = w1[c*9+j]; a2[j] = w2[c*9+j]; }
    float bb1 = b1[c], bb2 = b2[c], sc = asc[c];
    __syncthreads();
    for (int i = tid; i < 34*33; i += 256){
        int r = i / 33, chk = i - r*33;
        int cc0 = chk << 2;
        int y = r0 - 1 + r;
        bool yok = (unsigned)y < 128u;
        float o0 = 0.f, o1 = 0.f, o2 = 0.f, o3 = 0.f;
        if (yok){
            #pragma unroll
            for (int jr = 0; jr < 3; ++jr){
                const float* row = &it[(r + jr)*136 + cc0];
                floatx4 a = *(const floatx4*)row;
                float a4 = row[4], a5 = row[5];
                float w0 = a1[jr*3+0], w1v = a1[jr*3+1], w2v = a1[jr*3+2];
                o0 += w0*a[0] + w1v*a[1] + w2v*a[2];
                o1 += w0*a[1] + w1v*a[2] + w2v*a[3];
                o2 += w0*a[2] + w1v*a[3] + w2v*a4;
                o3 += w0*a[3] + w1v*a4  + w2v*a5;
            }
        }
        float* mrow = &mid[r*136 + cc0];
        mrow[0] = (yok && cc0+0 >= 1 && cc0+0 <= 128) ? fmaxf(o0 + bb1, 0.f) : 0.f;
        mrow[1] = (yok && cc0+1 >= 1 && cc0+1 <= 128) ? fmaxf(o1 + bb1, 0.f) : 0.f;
        mrow[2] = (yok && cc0+2 >= 1 && cc0+2 <= 128) ? fmaxf(o2 + bb1, 0.f) : 0.f;
        mrow[3] = (yok && cc0+3 >= 1 && cc0+3 <= 128) ? fmaxf(o3 + bb1, 0.f) : 0.f;
    }
    __syncthreads();
    float ps = 0.f, pq = 0.f;
    unsigned short* dst = plane + (size_t)bc*HWc;
    for (int i = tid; i < 32*32; i += 256){
        int yy = i >> 5, chk = i & 31;
        int x0 = chk << 2;
        float o0 = 0.f, o1 = 0.f, o2 = 0.f, o3 = 0.f;
        #pragma unroll
        for (int jr = 0; jr < 3; ++jr){
            const float* row = &mid[(yy + jr)*136 + x0];
            floatx4 a = *(const floatx4*)row;
            float a4 = row[4], a5 = row[5];
            float w0 = a2[jr*3+0], w1v = a2[jr*3+1], w2v = a2[jr*3+2];
            o0 += w0*a[0] + w1v*a[1] + w2v*a[2];
            o1 += w0*a[1] + w1v*a[2] + w2v*a[3];
            o2 += w0*a[2] + w1v*a[3] + w2v*a4;
            o3 += w0*a[3] + w1v*a4  + w2v*a5;
        }
        float v0 = o0 + bb2, v1 = o1 + bb2, v2 = o2 + bb2, v3 = o3 + bb2;
        ushort4v u;
        u[0] = f2h(v0); u[1] = f2h(v1); u[2] = f2h(v2); u[3] = f2h(v3);
        *(ushort4v*)(dst + ((r0 + yy) << 7) + x0) = u;
        float t0 = v0*sc, t1 = v1*sc, t2 = v2*sc, t3 = v3*sc;
        ps += t0 + t1 + t2 + t3;
        pq += t0*t0 + t1*t1 + t2*t2 + t3*t3;
    }
    __syncthreads();
    it[tid] = ps; it[256 + tid] = pq;
    __syncthreads();
    for (int s2 = 128; s2 > 0; s2 >>= 1){
        if (tid < s2){ it[tid] += it[tid+s2]; it[256+tid] += it[256+tid+s2]; }
        __syncthreads();
    }
    if (tid == 0){
        atomicAdd(&bnS[c], it[0]);
        atomicAdd(&bnQ[c], it[256]);
    }
}

// ---------------- K3t: BN fold + sigmoid gate + transpose plane -> attp fp16 [b][hw][c] ----------
__global__ __launch_bounds__(256) void k3t_att_t(const unsigned short* __restrict__ plane,
                                                 const float* __restrict__ bnS, const float* __restrict__ bnQ,
                                                 const float* __restrict__ asc,
                                                 const float* __restrict__ bng, const float* __restrict__ bnb,
                                                 unsigned short* __restrict__ attp){
    __shared__ float t[32*33];
    __shared__ float P_s[32], Q_s[32];
    int tid = threadIdx.x;
    int tx = tid & 31, ty = tid >> 5;
    int bi = blockIdx.x;
    int ht = bi & 511;
    int ct = (bi >> 9) & 7;
    int b  = bi >> 12;
    int c0 = ct << 5, h0 = ht << 5;
    if (tid < 32){
        int c = c0 + tid;
        float mean = bnS[c] * (1.f/32768.f);
        float var  = bnQ[c] * (1.f/32768.f) - mean*mean;
        float inv  = rsqrtf(fmaxf(var, 0.f) + 1e-5f) * bng[c];
        P_s[tid] = asc[c] * inv;
        Q_s[tid] = bnb[c] - mean * inv;
    }
    __syncthreads();
    for (int r = ty; r < 32; r += 8){
        int c = c0 + r;
        float v = h2f(plane[(((size_t)b << 8) + c)*HWc + h0 + tx]);
        float s = 1.f / (1.f + __expf(-(P_s[r]*v + Q_s[r])));
        t[r*33 + tx] = s * v;
    }
    __syncthreads();
    for (int r = ty; r < 32; r += 8){
        attp[(((size_t)b << 14) + h0 + r)*Cc + c0 + tx] = f2h(t[tx*33 + r]);
    }
}

// ---------------- K4 (old map, proven): for d0 (strided in) and d3 (strided out) ----------
__global__ __launch_bounds__(512, 4) void k4_cmix(const float* __restrict__ tsrc, int tin_nc,
                                               float* __restrict__ tdst, int tout_nc,
                                               const unsigned short* __restrict__ attp,
                                               const int* __restrict__ ci,
                                               const unsigned short* __restrict__ W1,
                                               const unsigned short* __restrict__ W2,
                                               const float* __restrict__ lng, const float* __restrict__ lnb,
                                               const float* __restrict__ b1, const float* __restrict__ b2,
                                               const float* __restrict__ csc,
                                               const float* __restrict__ lng2, const float* __restrict__ lnb2,
                                               const float* __restrict__ wptb,
                                               unsigned short* __restrict__ rbufn,
                                               int g, int g2, int donext){
    __shared__ __align__(16) unsigned short hs[64*264];
    __shared__ float reds[512], redq[512];
    __shared__ float m_s[64], r_s[64];
    __shared__ int cell_s[64];
    __shared__ float lng_s[Cc], lnb_s[Cc], b1_s[Cc], b2s_s[Cc], cs_s[Cc], g2g_s[Cc], g2b_s[Cc];

    int tid = threadIdx.x;
    int bi = blockIdx.x;
    int b = bi >> 9;
    int p0 = (bi & 511) << 6;

    if (tid < 256){
        lng_s[tid] = lng[tid];
        lnb_s[tid] = lnb[tid];
        b1_s[tid]  = b1[tid];
        float cv = csc[tid];
        cs_s[tid]  = cv;
        b2s_s[tid] = b2[tid] * cv;
        g2g_s[tid] = lng2[tid];
        g2b_s[tid] = lnb2[tid];
    }
    if (tid < 64){
        int cc = ci[(b*3 + g)*Nn + p0 + tid];
        cell_s[tid] = min(max(cc, 0), HWc-1);
    }
    __syncthreads();

    int p  = tid & 63;
    int cg = tid >> 6;
    int c0 = cg << 5;

    const unsigned short* ar = attp + ((size_t)((b << 14) + cell_s[p]))*Cc + c0;
    ushort8v rr[4];
    #pragma unroll
    for (int j = 0; j < 4; ++j) rr[j] = *(const ushort8v*)(ar + 8*j);

    float vreg[32];
    float sum = 0.f, sq = 0.f;
    if (tin_nc){
        const floatx4* tn4 = (const floatx4*)(tsrc + ((((size_t)(b << 15)) + p0 + p) << 8) + c0);
        #pragma unroll
        for (int j = 0; j < 8; ++j){
            floatx4 f = tn4[j];
            #pragma unroll
            for (int e = 0; e < 4; ++e){
                int k = j*4 + e;
                float v = f[e] + h2f(rr[k >> 3][k & 7]);
                vreg[k] = v; sum += v; sq += v*v;
            }
        }
    } else {
        const float* tb = tsrc + ((size_t)b << 8)*Nn + p0 + p;
        #pragma unroll
        for (int k = 0; k < 32; ++k){
            float v = tb[(size_t)(c0 + k) << 15] + h2f(rr[k >> 3][k & 7]);
            vreg[k] = v; sum += v; sq += v*v;
        }
    }
    reds[tid] = sum; redq[tid] = sq;
    __syncthreads();
    if (tid < 64){
        float s = 0.f, q = 0.f;
        #pragma unroll
        for (int j = 0; j < 8; ++j){ s += reds[j*64 + tid]; q += redq[j*64 + tid]; }
        float m = s * (1.f/256.f);
        float var = q * (1.f/256.f) - m*m;
        m_s[tid] = m;
        r_s[tid] = rsqrtf(fmaxf(var, 0.f) + 1e-5f);
    }
    __syncthreads();
    float mp = m_s[p], rp = r_s[p];
    unsigned short* hrow = &hs[p*264 + c0];
    #pragma unroll
    for (int j = 0; j < 4; ++j){
        ushort8v u;
        #pragma unroll
        for (int e = 0; e < 8; ++e){
            int k = j*8 + e, c = c0 + k;
            u[e] = f2b((vreg[k] - mp)*rp*lng_s[c] + lnb_s[c]);
        }
        *(ushort8v*)(hrow + 8*j) = u;
    }
    __syncthreads();

    int lane = tid & 63;
    int w = tid >> 6;
    int l15 = lane & 15;
    int q4 = lane >> 4;
    floatx4 acc[2][4];
    #pragma unroll
    for (int mi = 0; mi < 2; ++mi)
        #pragma unroll
        for (int ni = 0; ni < 4; ++ni)
            acc[mi][ni] = (floatx4){0.f, 0.f, 0.f, 0.f};

    #pragma unroll
    for (int kk = 0; kk < 8; ++kk){
        int k0 = kk*32 + q4*8;
        bf16x8 bfr[4];
        #pragma unroll
        for (int ni = 0; ni < 4; ++ni)
            bfr[ni] = *(const bf16x8*)&hs[(ni*16 + l15)*264 + k0];
        #pragma unroll
        for (int mi = 0; mi < 2; ++mi){
            bf16x8 af = *(const bf16x8*)&W1[(size_t)(w*32 + mi*16 + l15)*Cc + k0];
            #pragma unroll
            for (int ni = 0; ni < 4; ++ni)
                acc[mi][ni] = __builtin_amdgcn_mfma_f32_16x16x32_bf16(af, bfr[ni], acc[mi][ni], 0, 0, 0);
        }
    }
    __syncthreads();
    #pragma unroll
    for (int mi = 0; mi < 2; ++mi)
        #pragma unroll
        for (int ni = 0; ni < 4; ++ni){
            int m0 = w*32 + mi*16 + q4*4;
            int nn = ni*16 + l15;
            ushort4v u;
            #pragma unroll
            for (int r = 0; r < 4; ++r)
                u[r] = f2b(fmaxf(acc[mi][ni][r] + b1_s[m0 + r], 0.f));
            *(ushort4v*)&hs[nn*264 + m0] = u;
        }
    __syncthreads();

    #pragma unroll
    for (int mi = 0; mi < 2; ++mi)
        #pragma unroll
        for (int ni = 0; ni < 4; ++ni)
            acc[mi][ni] = (floatx4){0.f, 0.f, 0.f, 0.f};
    #pragma unroll
    for (int kk = 0; kk < 8; ++kk){
        int k0 = kk*32 + q4*8;
        bf16x8 bfr[4];
        #pragma unroll
        for (int ni = 0; ni < 4; ++ni)
            bfr[ni] = *(const bf16x8*)&hs[(ni*16 + l15)*264 + k0];
        #pragma unroll
        for (int mi = 0; mi < 2; ++mi){
            bf16x8 af = *(const bf16x8*)&W2[(size_t)(w*32 + mi*16 + l15)*Cc + k0];
            #pragma unroll
            for (int ni = 0; ni < 4; ++ni)
                acc[mi][ni] = __builtin_amdgcn_mfma_f32_16x16x32_bf16(af, bfr[ni], acc[mi][ni], 0, 0, 0);
        }
    }
    __syncthreads();
    #pragma unroll
    for (int mi = 0; mi < 2; ++mi)
        #pragma unroll
        for (int ni = 0; ni < 4; ++ni){
            int m0 = w*32 + mi*16 + q4*4;
            int nn = ni*16 + l15;
            ushort4v u;
            #pragma unroll
            for (int r = 0; r < 4; ++r)
                u[r] = f2b(acc[mi][ni][r]*cs_s[m0 + r] + b2s_s[m0 + r]);
            *(ushort4v*)&hs[nn*264 + m0] = u;
        }
    __syncthreads();

    float sum2 = 0.f, sq2 = 0.f;
    if (tout_nc){
        float* tn = tdst + ((((size_t)(b << 15)) + p0 + p) << 8) + c0;
        #pragma unroll
        for (int j = 0; j < 4; ++j){
            ushort8v u = *(const ushort8v*)(hrow + 8*j);
            floatx4 fa, fb;
            #pragma unroll
            for (int e = 0; e < 4; ++e){
                int k = j*8 + e;
                float v = vreg[k] + b2f(u[e]);
                vreg[k] = v; fa[e] = v; sum2 += v; sq2 += v*v;
            }
            #pragma unroll
            for (int e = 4; e < 8; ++e){
                int k = j*8 + e;
                float v = vreg[k] + b2f(u[e]);
                vreg[k] = v; fb[e-4] = v; sum2 += v; sq2 += v*v;
            }
            *(floatx4*)(tn + 8*j) = fa;
            *(floatx4*)(tn + 8*j + 4) = fb;
        }
    } else {
        float* ob = tdst + ((size_t)b << 8)*Nn + p0 + p;
        #pragma unroll
        for (int j = 0; j < 4; ++j){
            ushort8v u = *(const ushort8v*)(hrow + 8*j);
            #pragma unroll
            for (int e = 0; e < 8; ++e){
                int k = j*8 + e, c = c0 + k;
                float v = vreg[k] + b2f(u[e]);
                vreg[k] = v;
                ob[(size_t)c << 15] = v;
                sum2 += v; sq2 += v*v;
            }
        }
    }
    if (donext){
        reds[tid] = sum2; redq[tid] = sq2;
        __syncthreads();
        if (tid < 64){
            float s = 0.f, q = 0.f;
            #pragma unroll
            for (int j = 0; j < 8; ++j){ s += reds[j*64 + tid]; q += redq[j*64 + tid]; }
            float m = s * (1.f/256.f);
            float var = q * (1.f/256.f) - m*m;
            m_s[tid] = m;
            r_s[tid] = rsqrtf(fmaxf(var, 0.f) + 1e-5f);
        }
        __syncthreads();
        float m2 = m_s[p], rr2 = r_s[p];
        float wv2 = wptb[(b*3 + g2)*Nn + p0 + p];
        unsigned short* rb = rbufn + ((size_t)((b << 15) + p0 + p))*Cc + c0;
        #pragma unroll
        for (int j = 0; j < 4; ++j){
            ushort8v u;
            #pragma unroll
            for (int e = 0; e < 8; ++e){
                int k = j*8 + e, c = c0 + k;
                u[e] = f2h(((vreg[k] - m2)*rr2*g2g_s[c] + g2b_s[c]) * wv2);
            }
            *(ushort8v*)(rb + 8*j) = u;
        }
    }
}

// ---------------- K4_nc (row map): d1/d2 only — tnc in AND out, donext=1 ----------
// Wave-per-point I/O: lane owns 4 channels (c4 = lane*4). Every tnc/attp/rbuf access is a
// contiguous full-row vector op (64 lanes x 16B = one fp32 row; 8B/lane = one fp16 row).
// LN via 6-step shfl_xor. No vreg: epilogue recomputes residual from L2-hot re-reads + h2
// in LDS. 5 barriers (was 10).
__global__ __launch_bounds__(512, 4) void k4_cmix_nc(const float* __restrict__ tsrc,
                                               float* __restrict__ tdst,
                                               const unsigned short* __restrict__ attp,
                                               const int* __restrict__ ci,
                                               const unsigned short* __restrict__ W1,
                                               const unsigned short* __restrict__ W2,
                                               const float* __restrict__ lng, const float* __restrict__ lnb,
                                               const float* __restrict__ b1, const float* __restrict__ b2,
                                               const float* __restrict__ csc,
                                               const float* __restrict__ lng2, const float* __restrict__ lnb2,
                                               const float* __restrict__ wptb,
                                               unsigned short* __restrict__ rbufn,
                                               int g, int g2){
    __shared__ __align__(16) unsigned short hs[64*264];    // 33792 B
    __shared__ float b1_s[Cc], b2s_s[Cc], cs_s[Cc];        // 3072 B

    int tid = threadIdx.x;
    int lane = tid & 63;
    int w = tid >> 6;
    int bi = blockIdx.x;
    int b = bi >> 9;
    int p0 = (bi & 511) << 6;
    int c4 = lane << 2;

    if (tid < 256){
        b1_s[tid]  = b1[tid];
        float cv = csc[tid];
        cs_s[tid]  = cv;
        b2s_s[tid] = b2[tid] * cv;
    }

    floatx4 lngv = *(const floatx4*)&lng[c4];
    floatx4 lnbv = *(const floatx4*)&lnb[c4];

    int cells[8];
    const int pb = (b*3 + g)*Nn + p0 + w*8;
    #pragma unroll
    for (int i = 0; i < 8; ++i){
        int cc = ci[pb + i];
        cells[i] = min(max(cc, 0), HWc-1);
    }

    // ---- HEAD: gather + LN -> h (all coalesced full-row accesses) ----
    #pragma unroll
    for (int i = 0; i < 8; ++i){
        int p = w*8 + i;
        ushort4v av = *(const ushort4v*)(attp + ((size_t)((b << 14) + cells[i]))*Cc + c4);
        floatx4 tv = *(const floatx4*)(tsrc + ((size_t)((b << 15) + p0 + p))*Cc + c4);
        floatx4 v4;
        float s = 0.f, q = 0.f;
        #pragma unroll
        for (int e = 0; e < 4; ++e){
            float v = tv[e] + h2f(av[e]);
            v4[e] = v; s += v; q += v*v;
        }
        #pragma unroll
        for (int m = 1; m < 64; m <<= 1){
            s += __shfl_xor(s, m, 64);
            q += __shfl_xor(q, m, 64);
        }
        float mean = s * (1.f/256.f);
        float var  = q * (1.f/256.f) - mean*mean;
        float rinv = rsqrtf(fmaxf(var, 0.f) + 1e-5f);
        ushort4v u;
        #pragma unroll
        for (int e = 0; e < 4; ++e)
            u[e] = f2b((v4[e] - mean)*rinv*lngv[e] + lnbv[e]);
        *(ushort4v*)&hs[p*264 + c4] = u;
    }
    __syncthreads();   // h ready; b1_s etc staged

    int l15 = lane & 15;
    int q4 = lane >> 4;
    floatx4 acc[2][4];
    #pragma unroll
    for (int mi = 0; mi < 2; ++mi)
        #pragma unroll
        for (int ni = 0; ni < 4; ++ni)
            acc[mi][ni] = (floatx4){0.f, 0.f, 0.f, 0.f};

    // mm1
    #pragma unroll
    for (int kk = 0; kk < 8; ++kk){
        int k0 = kk*32 + q4*8;
        bf16x8 bfr[4];
        #pragma unroll
        for (int ni = 0; ni < 4; ++ni)
            bfr[ni] = *(const bf16x8*)&hs[(ni*16 + l15)*264 + k0];
        #pragma unroll
        for (int mi = 0; mi < 2; ++mi){
            bf16x8 af = *(const bf16x8*)&W1[(size_t)(w*32 + mi*16 + l15)*Cc + k0];
            #pragma unroll
            for (int ni = 0; ni < 4; ++ni)
                acc[mi][ni] = __builtin_amdgcn_mfma_f32_16x16x32_bf16(af, bfr[ni], acc[mi][ni], 0, 0, 0);
        }
    }
    __syncthreads();
    #pragma unroll
    for (int mi = 0; mi < 2; ++mi)
        #pragma unroll
        for (int ni = 0; ni < 4; ++ni){
            int m0 = w*32 + mi*16 + q4*4;
            int nn = ni*16 + l15;
            ushort4v u;
            #pragma unroll
            for (int r = 0; r < 4; ++r)
                u[r] = f2b(fmaxf(acc[mi][ni][r] + b1_s[m0 + r], 0.f));
            *(ushort4v*)&hs[nn*264 + m0] = u;
        }
    __syncthreads();

    // mm2
    #pragma unroll
    for (int mi = 0; mi < 2; ++mi)
        #pragma unroll
        for (int ni = 0; ni < 4; ++ni)
            acc[mi][ni] = (floatx4){0.f, 0.f, 0.f, 0.f};
    #pragma unroll
    for (int kk = 0; kk < 8; ++kk){
        int k0 = kk*32 + q4*8;
        bf16x8 bfr[4];
        #pragma unroll
        for (int ni = 0; ni < 4; ++ni)
            bfr[ni] = *(const bf16x8*)&hs[(ni*16 + l15)*264 + k0];
        #pragma unroll
        for (int mi = 0; mi < 2; ++mi){
            bf16x8 af = *(const bf16x8*)&W2[(size_t)(w*32 + mi*16 + l15)*Cc + k0];
            #pragma unroll
            for (int ni = 0; ni < 4; ++ni)
                acc[mi][ni] = __builtin_amdgcn_mfma_f32_16x16x32_bf16(af, bfr[ni], acc[mi][ni], 0, 0, 0);
        }
    }
    __syncthreads();
    #pragma unroll
    for (int mi = 0; mi < 2; ++mi)
        #pragma unroll
        for (int ni = 0; ni < 4; ++ni){
            int m0 = w*32 + mi*16 + q4*4;
            int nn = ni*16 + l15;
            ushort4v u;
            #pragma unroll
            for (int r = 0; r < 4; ++r)
                u[r] = f2b(acc[mi][ni][r]*cs_s[m0 + r] + b2s_s[m0 + r]);
            *(ushort4v*)&hs[nn*264 + m0] = u;
        }
    __syncthreads();   // h2 ready

    // ---- EPILOGUE: recompute residual (L2-hot re-reads) + h2; write tnc + rbuf coalesced ----
    floatx4 g2gv = *(const floatx4*)&lng2[c4];
    floatx4 g2bv = *(const floatx4*)&lnb2[c4];
    const int pb2 = (b*3 + g2)*Nn + p0 + w*8;
    #pragma unroll
    for (int i = 0; i < 8; ++i){
        int p = w*8 + i;
        ushort4v av = *(const ushort4v*)(attp + ((size_t)((b << 14) + cells[i]))*Cc + c4);
        floatx4 tv = *(const floatx4*)(tsrc + ((size_t)((b << 15) + p0 + p))*Cc + c4);
        ushort4v hv = *(const ushort4v*)&hs[p*264 + c4];
        floatx4 v4;
        float s = 0.f, q = 0.f;
        #pragma unroll
        for (int e = 0; e < 4; ++e){
            float v = tv[e] + h2f(av[e]) + b2f(hv[e]);
            v4[e] = v; s += v; q += v*v;
        }
        *(floatx4*)(tdst + ((size_t)((b << 15) + p0 + p))*Cc + c4) = v4;
        #pragma unroll
        for (int m = 1; m < 64; m <<= 1){
            s += __shfl_xor(s, m, 64);
            q += __shfl_xor(q, m, 64);
        }
        float mean = s * (1.f/256.f);
        float var  = q * (1.f/256.f) - mean*mean;
        float rinv = rsqrtf(fmaxf(var, 0.f) + 1e-5f);
        float wv = wptb[pb2 + i];
        ushort4v u;
        #pragma unroll
        for (int e = 0; e < 4; ++e)
            u[e] = f2h(((v4[e] - mean)*rinv*g2gv[e] + g2bv[e]) * wv);
        *(ushort4v*)(rbufn + ((size_t)((b << 15) + p0 + p))*Cc + c4) = u;
    }
}

extern "C" void kernel_launch(void* const* d_in, const int* in_sizes, int n_in,
                              void* d_out, int out_size, void* d_ws, size_t ws_size,
                              hipStream_t stream){
    (void)in_sizes; (void)n_in; (void)out_size;
    const float* tokens  = (const float*)d_in[0];
    const int*   cellind = (const int*)d_in[1];
    const float* occ     = (const float*)d_in[2];
    const float* smix_g  = (const float*)d_in[3];
    const float* smix_b  = (const float*)d_in[4];
    const float* ffn_w1  = (const float*)d_in[5];
    const float* ffn_b1  = (const float*)d_in[6];
    const float* ffn_w2  = (const float*)d_in[7];
    const float* ffn_b2  = (const float*)d_in[8];
    const float* att_sc  = (const float*)d_in[9];
    const float* bn_g    = (const float*)d_in[10];
    const float* bn_b    = (const float*)d_in[11];
    const float* cm_g    = (const float*)d_in[12];
    const float* cm_b    = (const float*)d_in[13];
    const float* cw1     = (const float*)d_in[14];
    const float* cb1     = (const float*)d_in[15];
    const float* cw2     = (const float*)d_in[16];
    const float* cb2     = (const float*)d_in[17];
    const float* cscale  = (const float*)d_in[18];
    float* out = (float*)d_out;
    char* w = (char*)d_ws;

    const size_t HGRID_BYTES = (size_t)Bb*Cc*HWc*2;          // 16777216
    unsigned short* grid_h  = (unsigned short*)(w);
    unsigned short* attp_h  = grid_h;                        // alias: grid dead after k2
    unsigned short* planeA  = (unsigned short*)(w + HGRID_BYTES);
    unsigned short* planeB  = (unsigned short*)(w + 2*HGRID_BYTES);
    unsigned short* rbuf    = (unsigned short*)(w + 3*HGRID_BYTES);  // [b][n][c] fp16, 33.5 MB
    size_t o = 3*HGRID_BYTES + (size_t)Bb*Nn*Cc*2;
    float* fcounts = (float*)(w + o); o += (size_t)Bb*3*HWc*4;
    int*   icounts = (int*)(w + o);   o += (size_t)Bb*3*HWc*4;
    float* wptb   = (float*)(w + o); o += (size_t)Bb*3*Nn*4;
    float* bnS    = (float*)(w + o);
    float* bnQ    = bnS + 256;
    o += 4096;
    unsigned short* W1b = (unsigned short*)(w + o);
    unsigned short* W2b = W1b + 4*Cc*Cc;
    o += (size_t)2*4*Cc*Cc*2;
    int* startsb  = (int*)(w + o); o += (size_t)Bb*3*STS*4;
    int* cursors  = (int*)(w + o); o += (size_t)Bb*3*HWc*4;
    int* plistb   = (int*)(w + o); o += (size_t)Bb*3*Nn*4;
    o = (o + 255) & ~(size_t)255;
    float* tnc    = (float*)(w + o);                         // [b][n][c] fp32 intermediate, 64 MB
    size_t needed = o + (size_t)Bb*Nn*Cc*4;
    int nc_ok = (ws_size >= needed) ? 1 : 0;

    // ---- setup (once per launch) ----
    hipMemsetAsync(fcounts, 0, (size_t)2*Bb*3*HWc*4, stream);
    k_count<<<(Bb*3*Nn)/256, 256, 0, stream>>>(cellind, occ, fcounts, icounts);
    k_scan<<<Bb*3, 256, 0, stream>>>(icounts, startsb, cursors);
    k_fill<<<(Bb*3*Nn)/256, 256, 0, stream>>>(cellind, occ, fcounts, cursors, plistb, wptb);
    k_wcvt<<<(4*Cc*Cc)/256, 256, 0, stream>>>(cw1, cw2, W1b, W2b);

    // depth-0 rbuf from input tokens
    k1a_ln<<<Bb*(Nn/64), 512, 0, stream>>>(tokens, wptb, smix_g, smix_b, rbuf, 0);

    for (int d = 0; d < 4; ++d){
        int g = d % 3;
        int g2 = (d + 1) % 3;
        int donext = (d < 3) ? 1 : 0;
        int useskip = (d == 3) ? 1 : 0;
        unsigned short* plane = (d == 0) ? planeA : planeB;
        int dn = (d + 1 < 4) ? d + 1 : d;

        const float* tsrc; int tin_nc;
        float* tdst; int tout_nc;
        if (nc_ok){
            tsrc = (d == 0) ? tokens : tnc;  tin_nc  = (d == 0) ? 0 : 1;
            tdst = (d == 3) ? out : tnc;     tout_nc = (d == 3) ? 0 : 1;
        } else {
            tsrc = (d == 0) ? tokens : out;  tin_nc  = 0;
            tdst = out;                      tout_nc = 0;
        }

        k1b_gather<<<Bb*(HWc/8), 256, 0, stream>>>(rbuf, startsb, plistb, grid_h, bnS, g);
        k2_conv<<<Bb*Cc*4, 256, 0, stream>>>(grid_h, planeA, plane,
                                             ffn_w1 + d*Cc*9, ffn_b1 + d*Cc,
                                             ffn_w2 + d*Cc*9, ffn_b2 + d*Cc,
                                             att_sc + d*Cc, bnS, bnQ, useskip);
        k3t_att_t<<<Bb*8*512, 256, 0, stream>>>(plane, bnS, bnQ, att_sc + d*Cc,
                                                bn_g + d*Cc, bn_b + d*Cc, attp_h);
        if (nc_ok && d >= 1 && d <= 2){
            // row-mapped variant: tnc in AND out, fully coalesced I/O
            k4_cmix_nc<<<Bb*(Nn/64), 512, 0, stream>>>(tnc, tnc, attp_h, cellind,
                                                W1b + (size_t)d*Cc*Cc, W2b + (size_t)d*Cc*Cc,
                                                cm_g + d*Cc, cm_b + d*Cc,
                                                cb1 + d*Cc, cb2 + d*Cc, cscale + d*Cc,
                                                smix_g + dn*Cc, smix_b + dn*Cc, wptb,
                                                rbuf, g, g2);
        } else {
            k4_cmix<<<Bb*(Nn/64), 512, 0, stream>>>(tsrc, tin_nc, tdst, tout_nc, attp_h, cellind,
                                                W1b + (size_t)d*Cc*Cc, W2b + (size_t)d*Cc*Cc,
                                                cm_g + d*Cc, cm_b + d*Cc,
                                                cb1 + d*Cc, cb2 + d*Cc, cscale + d*Cc,
                                                smix_g + dn*Cc, smix_b + dn*Cc, wptb,
                                                rbuf, g, g2, donext);
        }
    }
}

// Round 10
// 676.350 us; speedup vs baseline: 1.3623x; 1.0202x over previous
//
#include <hip/hip_runtime.h>
#include <hip/hip_bf16.h>
#include <hip/hip_fp16.h>

#define Cc 256
#define Nn 32768
#define HWc 16384
#define Bb 2
#define STS (HWc + 16)

typedef float floatx4 __attribute__((ext_vector_type(4)));
typedef short bf16x8 __attribute__((ext_vector_type(8)));
typedef unsigned short ushort8v __attribute__((ext_vector_type(8)));
typedef unsigned short ushort4v __attribute__((ext_vector_type(4)));
typedef int int4v __attribute__((ext_vector_type(4)));

__device__ __forceinline__ unsigned short f2b(float f){
    unsigned u = __float_as_uint(f);
    u += 0x7fff + ((u >> 16) & 1);
    return (unsigned short)(u >> 16);
}
__device__ __forceinline__ float b2f(unsigned short h){
    return __uint_as_float(((unsigned)h) << 16);
}
__device__ __forceinline__ unsigned short f2h(float f){
    return __half_as_ushort(__float2half(f));
}
__device__ __forceinline__ float h2f(unsigned short h){
    return __half2float(__ushort_as_half(h));
}

// ---------------- setup kernels ----------------
__global__ __launch_bounds__(256) void k_count(const int* __restrict__ ci,
                                               const float* __restrict__ occ,
                                               float* __restrict__ fcounts,
                                               int* __restrict__ icounts){
    int idx = blockIdx.x*256 + threadIdx.x;
    if (idx >= Bb*3*Nn) return;
    int n = idx & (Nn-1);
    int bg = idx >> 15;           // b*3+g
    int b = bg / 3;
    int cell = min(max(ci[idx], 0), HWc-1);
    float o = occ[(b<<15) + n];
    atomicAdd(&fcounts[(bg<<14) + cell], o*o);
    atomicAdd(&icounts[(bg<<14) + cell], 1);
}

// exclusive prefix scan of per-cell int counts -> starts[stride STS], cursors copy (int4)
__global__ __launch_bounds__(256) void k_scan(const int* __restrict__ ic,
                                              int* __restrict__ starts,
                                              int* __restrict__ cursor){
    __shared__ int part[256];
    int bg = blockIdx.x;          // 0..5
    int t = threadIdx.x;
    const int* cs = ic + (bg << 14);
    int4v buf[16];
    int s = 0;
    #pragma unroll
    for (int i = 0; i < 16; ++i){
        buf[i] = *(const int4v*)(cs + t*64 + i*4);
        s += buf[i][0] + buf[i][1] + buf[i][2] + buf[i][3];
    }
    part[t] = s;
    __syncthreads();
    for (int off = 1; off < 256; off <<= 1){
        int v = (t >= off) ? part[t - off] : 0;
        __syncthreads();
        part[t] += v;
        __syncthreads();
    }
    int run = (t == 0) ? 0 : part[t - 1];
    int* st = starts + bg * STS;
    int* cu = cursor + (bg << 14);
    #pragma unroll
    for (int i = 0; i < 16; ++i){
        int4v o;
        #pragma unroll
        for (int e = 0; e < 4; ++e){ o[e] = run; run += buf[i][e]; }
        *(int4v*)(st + t*64 + i*4) = o;
        *(int4v*)(cu + t*64 + i*4) = o;
    }
    if (t == 255) st[HWc] = run;
}

// fused: per-point weight (was k_wpt) + CSR fill
__global__ __launch_bounds__(256) void k_fill(const int* __restrict__ ci,
                                              const float* __restrict__ occ,
                                              const float* __restrict__ fcounts,
                                              int* __restrict__ cursor,
                                              int* __restrict__ plist,
                                              float* __restrict__ wpt){
    int idx = blockIdx.x*256 + threadIdx.x;
    if (idx >= Bb*3*Nn) return;
    int n = idx & (Nn-1);
    int bg = idx >> 15;
    int b = bg / 3;
    int cell = min(max(ci[idx], 0), HWc-1);
    float o = occ[(b<<15) + n];
    float cnt = fcounts[(bg<<14) + cell];
    wpt[idx] = o / (o*cnt + 1e-6f);
    int pos = atomicAdd(&cursor[(bg<<14) + cell], 1);
    plist[(bg<<15) + pos] = n;
}

__global__ __launch_bounds__(256) void k_wcvt(const float* __restrict__ w1,
                                              const float* __restrict__ w2,
                                              unsigned short* __restrict__ W1b,
                                              unsigned short* __restrict__ W2b){
    int idx = blockIdx.x*256 + threadIdx.x;
    if (idx >= 4*Cc*Cc) return;
    W1b[idx] = f2b(w1[idx]);
    W2b[idx] = f2b(w2[idx]);
}

// ---------------- K1a (depth 0 only): LayerNorm(smix) * wpt -> rbuf [b][n][c] fp16 ----------------
__global__ __launch_bounds__(512, 4) void k1a_ln(const float* __restrict__ tok,
                                              const float* __restrict__ wpt,
                                              const float* __restrict__ lng,
                                              const float* __restrict__ lnb,
                                              unsigned short* __restrict__ rbuf, int g){
    __shared__ float reds[512], redq[512];
    __shared__ float m_s[64], r_s[64];
    __shared__ float lg[Cc], lb[Cc];
    int tid = threadIdx.x;
    int bi = blockIdx.x;                 // Bb * (Nn/64)
    int b = bi >> 9;
    int p0 = (bi & 511) << 6;
    if (tid < 256){ lg[tid] = lng[tid]; lb[tid] = lnb[tid]; }
    int p  = tid & 63;
    int cg = tid >> 6;
    int c0 = cg << 5;
    const float* tb = tok + ((size_t)b << 8)*Nn + p0 + p;
    float vreg[32];
    float sum = 0.f, sq = 0.f;
    #pragma unroll
    for (int k = 0; k < 32; ++k){
        float v = tb[(size_t)(c0 + k) << 15];
        vreg[k] = v; sum += v; sq += v*v;
    }
    reds[tid] = sum; redq[tid] = sq;
    __syncthreads();
    if (tid < 64){
        float s = 0.f, q = 0.f;
        #pragma unroll
        for (int j = 0; j < 8; ++j){ s += reds[j*64 + tid]; q += redq[j*64 + tid]; }
        float m = s * (1.f/256.f);
        float var = q * (1.f/256.f) - m*m;
        m_s[tid] = m;
        r_s[tid] = rsqrtf(fmaxf(var, 0.f) + 1e-5f);
    }
    __syncthreads();
    float mp = m_s[p], rp = r_s[p];
    float wv = wpt[(b*3 + g)*Nn + p0 + p];
    unsigned short* rb = rbuf + ((size_t)((b << 15) + p0 + p))*Cc + c0;
    #pragma unroll
    for (int j = 0; j < 4; ++j){
        ushort8v u;
        #pragma unroll
        for (int e = 0; e < 8; ++e){
            int k = j*8 + e, c = c0 + k;
            u[e] = f2h(((vreg[k] - mp)*rp*lg[c] + lb[c]) * wv);
        }
        *(ushort8v*)(rb + 8*j) = u;
    }
}

// ---------------- K1b: CSR gather rbuf -> grid fp16 [b][c][hw], no atomics ----------------
__global__ __launch_bounds__(256) void k1b_gather(const unsigned short* __restrict__ rbuf,
                                                  const int* __restrict__ starts,
                                                  const int* __restrict__ plist,
                                                  unsigned short* __restrict__ grid,
                                                  float* __restrict__ bnSQ, int g){
    int t = threadIdx.x;                   // channel
    int bi = blockIdx.x;                   // Bb * (HW/8)
    if (bi == 0){ bnSQ[t] = 0.f; bnSQ[256 + t] = 0.f; }
    int b = bi >> 11;
    int cell0 = (bi & 2047) << 3;
    int bg = b*3 + g;
    const int* st = starts + bg*STS + cell0;
    const int* pl = plist + (bg << 15);
    const unsigned short* rb = rbuf + (((size_t)b << 15) << 8);
    float acc[8];
    int s0 = st[0];
    #pragma unroll
    for (int q = 0; q < 8; ++q){
        int s1 = st[q + 1];
        float a = 0.f;
        for (int j = s0; j < s1; ++j){
            int p = pl[j];
            a += h2f(rb[((size_t)p << 8) + t]);
        }
        acc[q] = a;
        s0 = s1;
    }
    unsigned short* go = grid + ((size_t)((b << 8) + t))*HWc + cell0;
    ushort8v u;
    #pragma unroll
    for (int e = 0; e < 8; ++e) u[e] = f2h(acc[e]);
    *(ushort8v*)go = u;
}

// ---------------- K2: fused dwconv3 -> relu -> dwconv3 (+skip) + BN partial sums (fp16 IO) ------
__global__ __launch_bounds__(256) void k2_conv(const unsigned short* __restrict__ grid,
                                               const unsigned short* __restrict__ skip,
                                               unsigned short* __restrict__ plane,
                                               const float* __restrict__ w1, const float* __restrict__ b1,
                                               const float* __restrict__ w2, const float* __restrict__ b2,
                                               const float* __restrict__ asc,
                                               float* __restrict__ bnS, float* __restrict__ bnQ,
                                               int useskip){
    __shared__ float it[36*136];
    __shared__ float mid[34*136];
    int tid = threadIdx.x;
    int bi = blockIdx.x;
    int rt = bi & 3;
    int bc = bi >> 2;              // b*256+c
    int c = bc & 255;
    int r0 = rt << 5;
    const unsigned short* src = grid + (size_t)bc*HWc;
    const unsigned short* sk  = skip + (size_t)bc*HWc;
    for (int i = tid; i < 36; i += 256){
        it[i*136 + 0] = 0.f;   it[i*136 + 1] = 0.f;
        it[i*136 + 130] = 0.f; it[i*136 + 131] = 0.f;
        it[i*136 + 132] = 0.f; it[i*136 + 133] = 0.f;
    }
    for (int i = tid; i < 36*16; i += 256){
        int r = i >> 4, ch = i & 15;
        int gy = r0 - 2 + r;
        float vals[8];
        #pragma unroll
        for (int e = 0; e < 8; ++e) vals[e] = 0.f;
        if ((unsigned)gy < 128u){
            ushort8v sv = *(const ushort8v*)(src + (gy << 7) + ch*8);
            if (useskip){
                ushort8v kv = *(const ushort8v*)(sk + (gy << 7) + ch*8);
                #pragma unroll
                for (int e = 0; e < 8; ++e) vals[e] = h2f(sv[e]) + h2f(kv[e]);
            } else {
                #pragma unroll
                for (int e = 0; e < 8; ++e) vals[e] = h2f(sv[e]);
            }
        }
        #pragma unroll
        for (int e = 0; e < 8; ++e) it[r*136 + 2 + ch*8 + e] = vals[e];
    }
    float a1[9], a2[9];
    #pragma unroll
    for (int j = 0; j < 9; ++j){ a1[j] = w1[c*9+j]; a2[j] = w2[c*9+j]; }
    float bb1 = b1[c], bb2 = b2[c], sc = asc[c];
    __syncthreads();
    for (int i = tid; i < 34*33; i += 256){
        int r = i / 33, chk = i - r*33;
        int cc0 = chk << 2;
        int y = r0 - 1 + r;
        bool yok = (unsigned)y < 128u;
        float o0 = 0.f, o1 = 0.f, o2 = 0.f, o3 = 0.f;
        if (yok){
            #pragma unroll
            for (int jr = 0; jr < 3; ++jr){
                const float* row = &it[(r + jr)*136 + cc0];
                floatx4 a = *(const floatx4*)row;
                float a4 = row[4], a5 = row[5];
                float w0 = a1[jr*3+0], w1v = a1[jr*3+1], w2v = a1[jr*3+2];
                o0 += w0*a[0] + w1v*a[1] + w2v*a[2];
                o1 += w0*a[1] + w1v*a[2] + w2v*a[3];
                o2 += w0*a[2] + w1v*a[3] + w2v*a4;
                o3 += w0*a[3] + w1v*a4  + w2v*a5;
            }
        }
        float* mrow = &mid[r*136 + cc0];
        mrow[0] = (yok && cc0+0 >= 1 && cc0+0 <= 128) ? fmaxf(o0 + bb1, 0.f) : 0.f;
        mrow[1] = (yok && cc0+1 >= 1 && cc0+1 <= 128) ? fmaxf(o1 + bb1, 0.f) : 0.f;
        mrow[2] = (yok && cc0+2 >= 1 && cc0+2 <= 128) ? fmaxf(o2 + bb1, 0.f) : 0.f;
        mrow[3] = (yok && cc0+3 >= 1 && cc0+3 <= 128) ? fmaxf(o3 + bb1, 0.f) : 0.f;
    }
    __syncthreads();
    float ps = 0.f, pq = 0.f;
    unsigned short* dst = plane + (size_t)bc*HWc;
    for (int i = tid; i < 32*32; i += 256){
        int yy = i >> 5, chk = i & 31;
        int x0 = chk << 2;
        float o0 = 0.f, o1 = 0.f, o2 = 0.f, o3 = 0.f;
        #pragma unroll
        for (int jr = 0; jr < 3; ++jr){
            const float* row = &mid[(yy + jr)*136 + x0];
            floatx4 a = *(const floatx4*)row;
            float a4 = row[4], a5 = row[5];
            float w0 = a2[jr*3+0], w1v = a2[jr*3+1], w2v = a2[jr*3+2];
            o0 += w0*a[0] + w1v*a[1] + w2v*a[2];
            o1 += w0*a[1] + w1v*a[2] + w2v*a[3];
            o2 += w0*a[2] + w1v*a[3] + w2v*a4;
            o3 += w0*a[3] + w1v*a4  + w2v*a5;
        }
        float v0 = o0 + bb2, v1 = o1 + bb2, v2 = o2 + bb2, v3 = o3 + bb2;
        ushort4v u;
        u[0] = f2h(v0); u[1] = f2h(v1); u[2] = f2h(v2); u[3] = f2h(v3);
        *(ushort4v*)(dst + ((r0 + yy) << 7) + x0) = u;
        float t0 = v0*sc, t1 = v1*sc, t2 = v2*sc, t3 = v3*sc;
        ps += t0 + t1 + t2 + t3;
        pq += t0*t0 + t1*t1 + t2*t2 + t3*t3;
    }
    __syncthreads();
    it[tid] = ps; it[256 + tid] = pq;
    __syncthreads();
    for (int s2 = 128; s2 > 0; s2 >>= 1){
        if (tid < s2){ it[tid] += it[tid+s2]; it[256+tid] += it[256+tid+s2]; }
        __syncthreads();
    }
    if (tid == 0){
        atomicAdd(&bnS[c], it[0]);
        atomicAdd(&bnQ[c], it[256]);
    }
}

// ---------------- K3t: BN fold + sigmoid gate + transpose plane -> attp fp16 [b][hw][c] ----------
__global__ __launch_bounds__(256) void k3t_att_t(const unsigned short* __restrict__ plane,
                                                 const float* __restrict__ bnS, const float* __restrict__ bnQ,
                                                 const float* __restrict__ asc,
                                                 const float* __restrict__ bng, const float* __restrict__ bnb,
                                                 unsigned short* __restrict__ attp){
    __shared__ float t[32*33];
    __shared__ float P_s[32], Q_s[32];
    int tid = threadIdx.x;
    int tx = tid & 31, ty = tid >> 5;
    int bi = blockIdx.x;
    int ht = bi & 511;
    int ct = (bi >> 9) & 7;
    int b  = bi >> 12;
    int c0 = ct << 5, h0 = ht << 5;
    if (tid < 32){
        int c = c0 + tid;
        float mean = bnS[c] * (1.f/32768.f);
        float var  = bnQ[c] * (1.f/32768.f) - mean*mean;
        float inv  = rsqrtf(fmaxf(var, 0.f) + 1e-5f) * bng[c];
        P_s[tid] = asc[c] * inv;
        Q_s[tid] = bnb[c] - mean * inv;
    }
    __syncthreads();
    for (int r = ty; r < 32; r += 8){
        int c = c0 + r;
        float v = h2f(plane[(((size_t)b << 8) + c)*HWc + h0 + tx]);
        float s = 1.f / (1.f + __expf(-(P_s[r]*v + Q_s[r])));
        t[r*33 + tx] = s * v;
    }
    __syncthreads();
    for (int r = ty; r < 32; r += 8){
        attp[(((size_t)b << 14) + h0 + r)*Cc + c0 + tx] = f2h(t[tx*33 + r]);
    }
}

// ---------------- K4 (old map, proven): for d0 (strided in) and d3 (strided out) ----------
__global__ __launch_bounds__(512, 4) void k4_cmix(const float* __restrict__ tsrc, int tin_nc,
                                               float* __restrict__ tdst, int tout_nc,
                                               const unsigned short* __restrict__ attp,
                                               const int* __restrict__ ci,
                                               const unsigned short* __restrict__ W1,
                                               const unsigned short* __restrict__ W2,
                                               const float* __restrict__ lng, const float* __restrict__ lnb,
                                               const float* __restrict__ b1, const float* __restrict__ b2,
                                               const float* __restrict__ csc,
                                               const float* __restrict__ lng2, const float* __restrict__ lnb2,
                                               const float* __restrict__ wptb,
                                               unsigned short* __restrict__ rbufn,
                                               int g, int g2, int donext){
    __shared__ __align__(16) unsigned short hs[64*264];
    __shared__ float reds[512], redq[512];
    __shared__ float m_s[64], r_s[64];
    __shared__ int cell_s[64];
    __shared__ float lng_s[Cc], lnb_s[Cc], b1_s[Cc], b2s_s[Cc], cs_s[Cc], g2g_s[Cc], g2b_s[Cc];

    int tid = threadIdx.x;
    int bi = blockIdx.x;
    int b = bi >> 9;
    int p0 = (bi & 511) << 6;

    if (tid < 256){
        lng_s[tid] = lng[tid];
        lnb_s[tid] = lnb[tid];
        b1_s[tid]  = b1[tid];
        float cv = csc[tid];
        cs_s[tid]  = cv;
        b2s_s[tid] = b2[tid] * cv;
        g2g_s[tid] = lng2[tid];
        g2b_s[tid] = lnb2[tid];
    }
    if (tid < 64){
        int cc = ci[(b*3 + g)*Nn + p0 + tid];
        cell_s[tid] = min(max(cc, 0), HWc-1);
    }
    __syncthreads();

    int p  = tid & 63;
    int cg = tid >> 6;
    int c0 = cg << 5;

    const unsigned short* ar = attp + ((size_t)((b << 14) + cell_s[p]))*Cc + c0;
    ushort8v rr[4];
    #pragma unroll
    for (int j = 0; j < 4; ++j) rr[j] = *(const ushort8v*)(ar + 8*j);

    float vreg[32];
    float sum = 0.f, sq = 0.f;
    if (tin_nc){
        const floatx4* tn4 = (const floatx4*)(tsrc + ((((size_t)(b << 15)) + p0 + p) << 8) + c0);
        #pragma unroll
        for (int j = 0; j < 8; ++j){
            floatx4 f = tn4[j];
            #pragma unroll
            for (int e = 0; e < 4; ++e){
                int k = j*4 + e;
                float v = f[e] + h2f(rr[k >> 3][k & 7]);
                vreg[k] = v; sum += v; sq += v*v;
            }
        }
    } else {
        const float* tb = tsrc + ((size_t)b << 8)*Nn + p0 + p;
        #pragma unroll
        for (int k = 0; k < 32; ++k){
            float v = tb[(size_t)(c0 + k) << 15] + h2f(rr[k >> 3][k & 7]);
            vreg[k] = v; sum += v; sq += v*v;
        }
    }
    reds[tid] = sum; redq[tid] = sq;
    __syncthreads();
    if (tid < 64){
        float s = 0.f, q = 0.f;
        #pragma unroll
        for (int j = 0; j < 8; ++j){ s += reds[j*64 + tid]; q += redq[j*64 + tid]; }
        float m = s * (1.f/256.f);
        float var = q * (1.f/256.f) - m*m;
        m_s[tid] = m;
        r_s[tid] = rsqrtf(fmaxf(var, 0.f) + 1e-5f);
    }
    __syncthreads();
    float mp = m_s[p], rp = r_s[p];
    unsigned short* hrow = &hs[p*264 + c0];
    #pragma unroll
    for (int j = 0; j < 4; ++j){
        ushort8v u;
        #pragma unroll
        for (int e = 0; e < 8; ++e){
            int k = j*8 + e, c = c0 + k;
            u[e] = f2b((vreg[k] - mp)*rp*lng_s[c] + lnb_s[c]);
        }
        *(ushort8v*)(hrow + 8*j) = u;
    }
    __syncthreads();

    int lane = tid & 63;
    int w = tid >> 6;
    int l15 = lane & 15;
    int q4 = lane >> 4;
    floatx4 acc[2][4];
    #pragma unroll
    for (int mi = 0; mi < 2; ++mi)
        #pragma unroll
        for (int ni = 0; ni < 4; ++ni)
            acc[mi][ni] = (floatx4){0.f, 0.f, 0.f, 0.f};

    #pragma unroll
    for (int kk = 0; kk < 8; ++kk){
        int k0 = kk*32 + q4*8;
        bf16x8 bfr[4];
        #pragma unroll
        for (int ni = 0; ni < 4; ++ni)
            bfr[ni] = *(const bf16x8*)&hs[(ni*16 + l15)*264 + k0];
        #pragma unroll
        for (int mi = 0; mi < 2; ++mi){
            bf16x8 af = *(const bf16x8*)&W1[(size_t)(w*32 + mi*16 + l15)*Cc + k0];
            #pragma unroll
            for (int ni = 0; ni < 4; ++ni)
                acc[mi][ni] = __builtin_amdgcn_mfma_f32_16x16x32_bf16(af, bfr[ni], acc[mi][ni], 0, 0, 0);
        }
    }
    __syncthreads();
    #pragma unroll
    for (int mi = 0; mi < 2; ++mi)
        #pragma unroll
        for (int ni = 0; ni < 4; ++ni){
            int m0 = w*32 + mi*16 + q4*4;
            int nn = ni*16 + l15;
            ushort4v u;
            #pragma unroll
            for (int r = 0; r < 4; ++r)
                u[r] = f2b(fmaxf(acc[mi][ni][r] + b1_s[m0 + r], 0.f));
            *(ushort4v*)&hs[nn*264 + m0] = u;
        }
    __syncthreads();

    #pragma unroll
    for (int mi = 0; mi < 2; ++mi)
        #pragma unroll
        for (int ni = 0; ni < 4; ++ni)
            acc[mi][ni] = (floatx4){0.f, 0.f, 0.f, 0.f};
    #pragma unroll
    for (int kk = 0; kk < 8; ++kk){
        int k0 = kk*32 + q4*8;
        bf16x8 bfr[4];
        #pragma unroll
        for (int ni = 0; ni < 4; ++ni)
            bfr[ni] = *(const bf16x8*)&hs[(ni*16 + l15)*264 + k0];
        #pragma unroll
        for (int mi = 0; mi < 2; ++mi){
            bf16x8 af = *(const bf16x8*)&W2[(size_t)(w*32 + mi*16 + l15)*Cc + k0];
            #pragma unroll
            for (int ni = 0; ni < 4; ++ni)
                acc[mi][ni] = __builtin_amdgcn_mfma_f32_16x16x32_bf16(af, bfr[ni], acc[mi][ni], 0, 0, 0);
        }
    }
    __syncthreads();
    #pragma unroll
    for (int mi = 0; mi < 2; ++mi)
        #pragma unroll
        for (int ni = 0; ni < 4; ++ni){
            int m0 = w*32 + mi*16 + q4*4;
            int nn = ni*16 + l15;
            ushort4v u;
            #pragma unroll
            for (int r = 0; r < 4; ++r)
                u[r] = f2b(acc[mi][ni][r]*cs_s[m0 + r] + b2s_s[m0 + r]);
            *(ushort4v*)&hs[nn*264 + m0] = u;
        }
    __syncthreads();

    float sum2 = 0.f, sq2 = 0.f;
    if (tout_nc){
        float* tn = tdst + ((((size_t)(b << 15)) + p0 + p) << 8) + c0;
        #pragma unroll
        for (int j = 0; j < 4; ++j){
            ushort8v u = *(const ushort8v*)(hrow + 8*j);
            floatx4 fa, fb;
            #pragma unroll
            for (int e = 0; e < 4; ++e){
                int k = j*8 + e;
                float v = vreg[k] + b2f(u[e]);
                vreg[k] = v; fa[e] = v; sum2 += v; sq2 += v*v;
            }
            #pragma unroll
            for (int e = 4; e < 8; ++e){
                int k = j*8 + e;
                float v = vreg[k] + b2f(u[e]);
                vreg[k] = v; fb[e-4] = v; sum2 += v; sq2 += v*v;
            }
            *(floatx4*)(tn + 8*j) = fa;
            *(floatx4*)(tn + 8*j + 4) = fb;
        }
    } else {
        float* ob = tdst + ((size_t)b << 8)*Nn + p0 + p;
        #pragma unroll
        for (int j = 0; j < 4; ++j){
            ushort8v u = *(const ushort8v*)(hrow + 8*j);
            #pragma unroll
            for (int e = 0; e < 8; ++e){
                int k = j*8 + e, c = c0 + k;
                float v = vreg[k] + b2f(u[e]);
                vreg[k] = v;
                ob[(size_t)c << 15] = v;
                sum2 += v; sq2 += v*v;
            }
        }
    }
    if (donext){
        reds[tid] = sum2; redq[tid] = sq2;
        __syncthreads();
        if (tid < 64){
            float s = 0.f, q = 0.f;
            #pragma unroll
            for (int j = 0; j < 8; ++j){ s += reds[j*64 + tid]; q += redq[j*64 + tid]; }
            float m = s * (1.f/256.f);
            float var = q * (1.f/256.f) - m*m;
            m_s[tid] = m;
            r_s[tid] = rsqrtf(fmaxf(var, 0.f) + 1e-5f);
        }
        __syncthreads();
        float m2 = m_s[p], rr2 = r_s[p];
        float wv2 = wptb[(b*3 + g2)*Nn + p0 + p];
        unsigned short* rb = rbufn + ((size_t)((b << 15) + p0 + p))*Cc + c0;
        #pragma unroll
        for (int j = 0; j < 4; ++j){
            ushort8v u;
            #pragma unroll
            for (int e = 0; e < 8; ++e){
                int k = j*8 + e, c = c0 + k;
                u[e] = f2h(((vreg[k] - m2)*rr2*g2g_s[c] + g2b_s[c]) * wv2);
            }
            *(ushort8v*)(rb + 8*j) = u;
        }
    }
}

// ---------------- K4_nc (row map): d1/d2 only — tnc in AND out, donext=1 ----------
// Wave-per-point I/O: lane owns 4 channels (c4 = lane*4). Every tnc/attp/rbuf access is a
// contiguous full-row vector op. Residual kept in vreg[32] (8 pts x 4 ch) — no epilogue
// re-reads (R9 lesson: "L2-hot" recompute cost +40MB real HBM traffic).
__global__ __launch_bounds__(512, 4) void k4_cmix_nc(const float* __restrict__ tsrc,
                                               float* __restrict__ tdst,
                                               const unsigned short* __restrict__ attp,
                                               const int* __restrict__ ci,
                                               const unsigned short* __restrict__ W1,
                                               const unsigned short* __restrict__ W2,
                                               const float* __restrict__ lng, const float* __restrict__ lnb,
                                               const float* __restrict__ b1, const float* __restrict__ b2,
                                               const float* __restrict__ csc,
                                               const float* __restrict__ lng2, const float* __restrict__ lnb2,
                                               const float* __restrict__ wptb,
                                               unsigned short* __restrict__ rbufn,
                                               int g, int g2){
    __shared__ __align__(16) unsigned short hs[64*264];    // 33792 B
    __shared__ float b1_s[Cc], b2s_s[Cc], cs_s[Cc];        // 3072 B

    int tid = threadIdx.x;
    int lane = tid & 63;
    int w = tid >> 6;
    int bi = blockIdx.x;
    int b = bi >> 9;
    int p0 = (bi & 511) << 6;
    int c4 = lane << 2;

    if (tid < 256){
        b1_s[tid]  = b1[tid];
        float cv = csc[tid];
        cs_s[tid]  = cv;
        b2s_s[tid] = b2[tid] * cv;
    }

    floatx4 lngv = *(const floatx4*)&lng[c4];
    floatx4 lnbv = *(const floatx4*)&lnb[c4];

    float vreg[32];   // residual: 8 points x 4 channels
    const int pb = (b*3 + g)*Nn + p0 + w*8;

    // ---- HEAD: gather + LN -> h (all coalesced full-row accesses) ----
    #pragma unroll
    for (int i = 0; i < 8; ++i){
        int p = w*8 + i;
        int cell = ci[pb + i];
        cell = min(max(cell, 0), HWc-1);
        ushort4v av = *(const ushort4v*)(attp + ((size_t)((b << 14) + cell))*Cc + c4);
        floatx4 tv = *(const floatx4*)(tsrc + ((size_t)((b << 15) + p0 + p))*Cc + c4);
        float s = 0.f, q = 0.f;
        #pragma unroll
        for (int e = 0; e < 4; ++e){
            float v = tv[e] + h2f(av[e]);
            vreg[i*4 + e] = v; s += v; q += v*v;
        }
        #pragma unroll
        for (int m = 1; m < 64; m <<= 1){
            s += __shfl_xor(s, m, 64);
            q += __shfl_xor(q, m, 64);
        }
        float mean = s * (1.f/256.f);
        float var  = q * (1.f/256.f) - mean*mean;
        float rinv = rsqrtf(fmaxf(var, 0.f) + 1e-5f);
        ushort4v u;
        #pragma unroll
        for (int e = 0; e < 4; ++e)
            u[e] = f2b((vreg[i*4 + e] - mean)*rinv*lngv[e] + lnbv[e]);
        *(ushort4v*)&hs[p*264 + c4] = u;
    }
    __syncthreads();   // h ready; b1_s etc staged

    int l15 = lane & 15;
    int q4 = lane >> 4;
    floatx4 acc[2][4];
    #pragma unroll
    for (int mi = 0; mi < 2; ++mi)
        #pragma unroll
        for (int ni = 0; ni < 4; ++ni)
            acc[mi][ni] = (floatx4){0.f, 0.f, 0.f, 0.f};

    // mm1
    #pragma unroll
    for (int kk = 0; kk < 8; ++kk){
        int k0 = kk*32 + q4*8;
        bf16x8 bfr[4];
        #pragma unroll
        for (int ni = 0; ni < 4; ++ni)
            bfr[ni] = *(const bf16x8*)&hs[(ni*16 + l15)*264 + k0];
        #pragma unroll
        for (int mi = 0; mi < 2; ++mi){
            bf16x8 af = *(const bf16x8*)&W1[(size_t)(w*32 + mi*16 + l15)*Cc + k0];
            #pragma unroll
            for (int ni = 0; ni < 4; ++ni)
                acc[mi][ni] = __builtin_amdgcn_mfma_f32_16x16x32_bf16(af, bfr[ni], acc[mi][ni], 0, 0, 0);
        }
    }
    __syncthreads();
    #pragma unroll
    for (int mi = 0; mi < 2; ++mi)
        #pragma unroll
        for (int ni = 0; ni < 4; ++ni){
            int m0 = w*32 + mi*16 + q4*4;
            int nn = ni*16 + l15;
            ushort4v u;
            #pragma unroll
            for (int r = 0; r < 4; ++r)
                u[r] = f2b(fmaxf(acc[mi][ni][r] + b1_s[m0 + r], 0.f));
            *(ushort4v*)&hs[nn*264 + m0] = u;
        }
    __syncthreads();

    // mm2
    #pragma unroll
    for (int mi = 0; mi < 2; ++mi)
        #pragma unroll
        for (int ni = 0; ni < 4; ++ni)
            acc[mi][ni] = (floatx4){0.f, 0.f, 0.f, 0.f};
    #pragma unroll
    for (int kk = 0; kk < 8; ++kk){
        int k0 = kk*32 + q4*8;
        bf16x8 bfr[4];
        #pragma unroll
        for (int ni = 0; ni < 4; ++ni)
            bfr[ni] = *(const bf16x8*)&hs[(ni*16 + l15)*264 + k0];
        #pragma unroll
        for (int mi = 0; mi < 2; ++mi){
            bf16x8 af = *(const bf16x8*)&W2[(size_t)(w*32 + mi*16 + l15)*Cc + k0];
            #pragma unroll
            for (int ni = 0; ni < 4; ++ni)
                acc[mi][ni] = __builtin_amdgcn_mfma_f32_16x16x32_bf16(af, bfr[ni], acc[mi][ni], 0, 0, 0);
        }
    }
    __syncthreads();
    #pragma unroll
    for (int mi = 0; mi < 2; ++mi)
        #pragma unroll
        for (int ni = 0; ni < 4; ++ni){
            int m0 = w*32 + mi*16 + q4*4;
            int nn = ni*16 + l15;
            ushort4v u;
            #pragma unroll
            for (int r = 0; r < 4; ++r)
                u[r] = f2b(acc[mi][ni][r]*cs_s[m0 + r] + b2s_s[m0 + r]);
            *(ushort4v*)&hs[nn*264 + m0] = u;
        }
    __syncthreads();   // h2 ready

    // ---- EPILOGUE: residual from vreg + h2; write tnc + rbuf coalesced ----
    floatx4 g2gv = *(const floatx4*)&lng2[c4];
    floatx4 g2bv = *(const floatx4*)&lnb2[c4];
    const int pb2 = (b*3 + g2)*Nn + p0 + w*8;
    #pragma unroll
    for (int i = 0; i < 8; ++i){
        int p = w*8 + i;
        ushort4v hv = *(const ushort4v*)&hs[p*264 + c4];
        floatx4 v4;
        float s = 0.f, q = 0.f;
        #pragma unroll
        for (int e = 0; e < 4; ++e){
            float v = vreg[i*4 + e] + b2f(hv[e]);
            v4[e] = v; s += v; q += v*v;
        }
        *(floatx4*)(tdst + ((size_t)((b << 15) + p0 + p))*Cc + c4) = v4;
        #pragma unroll
        for (int m = 1; m < 64; m <<= 1){
            s += __shfl_xor(s, m, 64);
            q += __shfl_xor(q, m, 64);
        }
        float mean = s * (1.f/256.f);
        float var  = q * (1.f/256.f) - mean*mean;
        float rinv = rsqrtf(fmaxf(var, 0.f) + 1e-5f);
        float wv = wptb[pb2 + i];
        ushort4v u;
        #pragma unroll
        for (int e = 0; e < 4; ++e)
            u[e] = f2h(((v4[e] - mean)*rinv*g2gv[e] + g2bv[e]) * wv);
        *(ushort4v*)(rbufn + ((size_t)((b << 15) + p0 + p))*Cc + c4) = u;
    }
}

extern "C" void kernel_launch(void* const* d_in, const int* in_sizes, int n_in,
                              void* d_out, int out_size, void* d_ws, size_t ws_size,
                              hipStream_t stream){
    (void)in_sizes; (void)n_in; (void)out_size;
    const float* tokens  = (const float*)d_in[0];
    const int*   cellind = (const int*)d_in[1];
    const float* occ     = (const float*)d_in[2];
    const float* smix_g  = (const float*)d_in[3];
    const float* smix_b  = (const float*)d_in[4];
    const float* ffn_w1  = (const float*)d_in[5];
    const float* ffn_b1  = (const float*)d_in[6];
    const float* ffn_w2  = (const float*)d_in[7];
    const float* ffn_b2  = (const float*)d_in[8];
    const float* att_sc  = (const float*)d_in[9];
    const float* bn_g    = (const float*)d_in[10];
    const float* bn_b    = (const float*)d_in[11];
    const float* cm_g    = (const float*)d_in[12];
    const float* cm_b    = (const float*)d_in[13];
    const float* cw1     = (const float*)d_in[14];
    const float* cb1     = (const float*)d_in[15];
    const float* cw2     = (const float*)d_in[16];
    const float* cb2     = (const float*)d_in[17];
    const float* cscale  = (const float*)d_in[18];
    float* out = (float*)d_out;
    char* w = (char*)d_ws;

    const size_t HGRID_BYTES = (size_t)Bb*Cc*HWc*2;          // 16777216
    unsigned short* grid_h  = (unsigned short*)(w);
    unsigned short* attp_h  = grid_h;                        // alias: grid dead after k2
    unsigned short* planeA  = (unsigned short*)(w + HGRID_BYTES);
    unsigned short* planeB  = (unsigned short*)(w + 2*HGRID_BYTES);
    unsigned short* rbuf    = (unsigned short*)(w + 3*HGRID_BYTES);  // [b][n][c] fp16, 33.5 MB
    size_t o = 3*HGRID_BYTES + (size_t)Bb*Nn*Cc*2;
    float* fcounts = (float*)(w + o); o += (size_t)Bb*3*HWc*4;
    int*   icounts = (int*)(w + o);   o += (size_t)Bb*3*HWc*4;
    float* wptb   = (float*)(w + o); o += (size_t)Bb*3*Nn*4;
    float* bnS    = (float*)(w + o);
    float* bnQ    = bnS + 256;
    o += 4096;
    unsigned short* W1b = (unsigned short*)(w + o);
    unsigned short* W2b = W1b + 4*Cc*Cc;
    o += (size_t)2*4*Cc*Cc*2;
    int* startsb  = (int*)(w + o); o += (size_t)Bb*3*STS*4;
    int* cursors  = (int*)(w + o); o += (size_t)Bb*3*HWc*4;
    int* plistb   = (int*)(w + o); o += (size_t)Bb*3*Nn*4;
    o = (o + 255) & ~(size_t)255;
    float* tnc    = (float*)(w + o);                         // [b][n][c] fp32 intermediate, 64 MB
    size_t needed = o + (size_t)Bb*Nn*Cc*4;
    int nc_ok = (ws_size >= needed) ? 1 : 0;

    // ---- setup (once per launch) ----
    hipMemsetAsync(fcounts, 0, (size_t)2*Bb*3*HWc*4, stream);
    k_count<<<(Bb*3*Nn)/256, 256, 0, stream>>>(cellind, occ, fcounts, icounts);
    k_scan<<<Bb*3, 256, 0, stream>>>(icounts, startsb, cursors);
    k_fill<<<(Bb*3*Nn)/256, 256, 0, stream>>>(cellind, occ, fcounts, cursors, plistb, wptb);
    k_wcvt<<<(4*Cc*Cc)/256, 256, 0, stream>>>(cw1, cw2, W1b, W2b);

    // depth-0 rbuf from input tokens
    k1a_ln<<<Bb*(Nn/64), 512, 0, stream>>>(tokens, wptb, smix_g, smix_b, rbuf, 0);

    for (int d = 0; d < 4; ++d){
        int g = d % 3;
        int g2 = (d + 1) % 3;
        int donext = (d < 3) ? 1 : 0;
        int useskip = (d == 3) ? 1 : 0;
        unsigned short* plane = (d == 0) ? planeA : planeB;
        int dn = (d + 1 < 4) ? d + 1 : d;

        const float* tsrc; int tin_nc;
        float* tdst; int tout_nc;
        if (nc_ok){
            tsrc = (d == 0) ? tokens : tnc;  tin_nc  = (d == 0) ? 0 : 1;
            tdst = (d == 3) ? out : tnc;     tout_nc = (d == 3) ? 0 : 1;
        } else {
            tsrc = (d == 0) ? tokens : out;  tin_nc  = 0;
            tdst = out;                      tout_nc = 0;
        }

        k1b_gather<<<Bb*(HWc/8), 256, 0, stream>>>(rbuf, startsb, plistb, grid_h, bnS, g);
        k2_conv<<<Bb*Cc*4, 256, 0, stream>>>(grid_h, planeA, plane,
                                             ffn_w1 + d*Cc*9, ffn_b1 + d*Cc,
                                             ffn_w2 + d*Cc*9, ffn_b2 + d*Cc,
                                             att_sc + d*Cc, bnS, bnQ, useskip);
        k3t_att_t<<<Bb*8*512, 256, 0, stream>>>(plane, bnS, bnQ, att_sc + d*Cc,
                                                bn_g + d*Cc, bn_b + d*Cc, attp_h);
        if (nc_ok && d >= 1 && d <= 2){
            // row-mapped variant: tnc in AND out, fully coalesced I/O, residual in regs
            k4_cmix_nc<<<Bb*(Nn/64), 512, 0, stream>>>(tnc, tnc, attp_h, cellind,
                                                W1b + (size_t)d*Cc*Cc, W2b + (size_t)d*Cc*Cc,
                                                cm_g + d*Cc, cm_b + d*Cc,
                                                cb1 + d*Cc, cb2 + d*Cc, cscale + d*Cc,
                                                smix_g + dn*Cc, smix_b + dn*Cc, wptb,
                                                rbuf, g, g2);
        } else {
            k4_cmix<<<Bb*(Nn/64), 512, 0, stream>>>(tsrc, tin_nc, tdst, tout_nc, attp_h, cellind,
                                                W1b + (size_t)d*Cc*Cc, W2b + (size_t)d*Cc*Cc,
                                                cm_g + d*Cc, cm_b + d*Cc,
                                                cb1 + d*Cc, cb2 + d*Cc, cscale + d*Cc,
                                                smix_g + dn*Cc, smix_b + dn*Cc, wptb,
                                                rbuf, g, g2, donext);
        }
    }
}